// Round 1
// baseline (11462.042 us; speedup 1.0000x reference)
//
#include <hip/hip_runtime.h>
#include <math.h>

// Problem constants (Compress_30047591202836)
constexpr int S_   = 2048;
constexpr int H_   = 2048;
constexpr int NH_  = 32;
constexpr int NKV_ = 8;
constexpr int HD_  = 64;
constexpr int GROUPS_ = NH_ / NKV_;     // 4
constexpr int KV_  = NKV_ * HD_;        // 512
constexpr int COMP_ = 1024;             // S * 0.5
constexpr int FF_  = 5632;
constexpr int TOT_ = S_ + COMP_;        // 3072
constexpr float EPS_ = 1e-6f;

// ---------------------------------------------------------------------------
// Generic fp32 GEMM:  C[M,N] = A[M,K] @ B + (bias per row) + (addp elementwise)
//   BT=true : B is (N,K) row-major  (i.e. C = A @ B^T — all weight matmuls)
//   BT=false: B is (K,N) row-major  (i.e. C = A @ B   — the compression matmul)
// Tile 64x64, BK=16, 256 threads, 4x4 accumulators per thread.
// Requires M%64==0, N%64==0, K%16==0 (true for all shapes here).
// ---------------------------------------------------------------------------
template <bool BT>
__global__ __launch_bounds__(256) void gemm64(
    const float* __restrict__ A, const float* __restrict__ Bm,
    const float* __restrict__ addp, const float* __restrict__ bias,
    float* __restrict__ C, int M, int N, int K)
{
    __shared__ float As[16][68];   // [k][m], +4 pad keeps float4 alignment
    __shared__ float Bs[16][68];   // [k][n]

    const int tid = threadIdx.x;
    const int bm = blockIdx.y, bn = blockIdx.x;
    const int tx = tid & 15, ty = tid >> 4;

    // loader indices
    const int lr = tid >> 2;          // 0..63 : tile row (A and BT-B)
    const int lk = (tid & 3) << 2;    // 0,4,8,12 : k-offset
    const int bkr = tid >> 4;         // 0..15 : k row (NN-B)
    const int bkc = (tid & 15) << 2;  // 0..60 : n-offset (NN-B)

    float acc[4][4] = {};

    for (int k0 = 0; k0 < K; k0 += 16) {
        float4 av = *(const float4*)&A[(size_t)(bm * 64 + lr) * K + k0 + lk];
        float4 bv;
        if (BT) {
            bv = *(const float4*)&Bm[(size_t)(bn * 64 + lr) * K + k0 + lk];
        } else {
            bv = *(const float4*)&Bm[(size_t)(k0 + bkr) * N + bn * 64 + bkc];
        }
        __syncthreads();   // previous iteration's compute done before overwrite
        As[lk + 0][lr] = av.x;
        As[lk + 1][lr] = av.y;
        As[lk + 2][lr] = av.z;
        As[lk + 3][lr] = av.w;
        if (BT) {
            Bs[lk + 0][lr] = bv.x;
            Bs[lk + 1][lr] = bv.y;
            Bs[lk + 2][lr] = bv.z;
            Bs[lk + 3][lr] = bv.w;
        } else {
            *(float4*)&Bs[bkr][bkc] = bv;
        }
        __syncthreads();

#pragma unroll
        for (int kk = 0; kk < 16; kk++) {
            float4 a = *(float4*)&As[kk][ty * 4];
            float4 b = *(float4*)&Bs[kk][tx * 4];
            float ar[4] = {a.x, a.y, a.z, a.w};
            float br[4] = {b.x, b.y, b.z, b.w};
#pragma unroll
            for (int i = 0; i < 4; i++)
#pragma unroll
                for (int j = 0; j < 4; j++)
                    acc[i][j] = fmaf(ar[i], br[j], acc[i][j]);
        }
    }

#pragma unroll
    for (int i = 0; i < 4; i++) {
        const int row = bm * 64 + ty * 4 + i;
        const int col = bn * 64 + tx * 4;
        float4 r = {acc[i][0], acc[i][1], acc[i][2], acc[i][3]};
        if (bias) {
            const float bb = bias[row];
            r.x += bb; r.y += bb; r.z += bb; r.w += bb;
        }
        if (addp) {
            float4 ad = *(const float4*)&addp[(size_t)row * N + col];
            r.x += ad.x; r.y += ad.y; r.z += ad.z; r.w += ad.w;
        }
        *(float4*)&C[(size_t)row * N + col] = r;
    }
}

// ---------------------------------------------------------------------------
// RMSNorm over rows of length H_=2048. One block (256 threads) per row.
// ---------------------------------------------------------------------------
__global__ __launch_bounds__(256) void rmsnorm_k(
    const float* __restrict__ x, const float* __restrict__ w,
    float* __restrict__ y)
{
    const int row = blockIdx.x;
    const float* xr = x + (size_t)row * H_;
    __shared__ float red[256];

    float s = 0.f;
#pragma unroll
    for (int i = 0; i < 8; i++) {
        const float v = xr[threadIdx.x + i * 256];
        s += v * v;
    }
    red[threadIdx.x] = s;
    __syncthreads();
    for (int t = 128; t > 0; t >>= 1) {
        if (threadIdx.x < t) red[threadIdx.x] += red[threadIdx.x + t];
        __syncthreads();
    }
    const float scale = rsqrtf(red[0] * (1.0f / H_) + EPS_);
#pragma unroll
    for (int i = 0; i < 8; i++) {
        const int idx = threadIdx.x + i * 256;
        y[(size_t)row * H_ + idx] = xr[idx] * scale * w[idx];
    }
}

// ---------------------------------------------------------------------------
// GQA attention, no mask, full softmax over TOT_=3072 keys.
// One block (256 threads) per (q_row, head). Exact two-pass softmax.
//   q: (COMP_, H_)   k,v: (TOT_, KV_)   o: (COMP_, H_)
// ---------------------------------------------------------------------------
__global__ __launch_bounds__(256) void attn_k(
    const float* __restrict__ q, const float* __restrict__ k,
    const float* __restrict__ v, float* __restrict__ o)
{
    const int r = blockIdx.x;      // 0..COMP_-1
    const int h = blockIdx.y;      // 0..NH_-1
    const int kvh = h / GROUPS_;
    const int tid = threadIdx.x;

    __shared__ float qs[HD_];
    __shared__ float sc[TOT_];     // 12 KB
    __shared__ float red[256];
    __shared__ float part[4][HD_];

    if (tid < HD_) qs[tid] = q[(size_t)r * H_ + h * HD_ + tid];
    __syncthreads();

    constexpr float scale = 0.125f;  // 1/sqrt(64)
    float ls[12];
    float lmax = -1e30f;
#pragma unroll
    for (int i = 0; i < 12; i++) {
        const int t = tid + i * 256;
        const float* kp = &k[(size_t)t * KV_ + kvh * HD_];
        float d = 0.f;
#pragma unroll
        for (int dd = 0; dd < HD_ / 4; dd++) {
            const float4 kv4 = *(const float4*)&kp[dd * 4];
            d = fmaf(qs[dd * 4 + 0], kv4.x, d);
            d = fmaf(qs[dd * 4 + 1], kv4.y, d);
            d = fmaf(qs[dd * 4 + 2], kv4.z, d);
            d = fmaf(qs[dd * 4 + 3], kv4.w, d);
        }
        d *= scale;
        ls[i] = d;
        lmax = fmaxf(lmax, d);
    }
    red[tid] = lmax;
    __syncthreads();
    for (int t = 128; t > 0; t >>= 1) {
        if (tid < t) red[tid] = fmaxf(red[tid], red[tid + t]);
        __syncthreads();
    }
    const float mx = red[0];
    __syncthreads();

    float lsum = 0.f;
#pragma unroll
    for (int i = 0; i < 12; i++) {
        const float e = __expf(ls[i] - mx);
        sc[tid + i * 256] = e;
        lsum += e;
    }
    red[tid] = lsum;
    __syncthreads();
    for (int t = 128; t > 0; t >>= 1) {
        if (tid < t) red[tid] += red[tid + t];
        __syncthreads();
    }
    const float inv = 1.0f / red[0];

    // PV: thread (p,d) accumulates quarter p of the t-range for dim d
    const int d = tid & 63, p = tid >> 6;
    float accv = 0.f;
    const int t0 = p * (TOT_ / 4);
    for (int t = t0; t < t0 + TOT_ / 4; t++)
        accv = fmaf(sc[t], v[(size_t)t * KV_ + kvh * HD_ + d], accv);
    part[p][d] = accv;
    __syncthreads();
    if (tid < HD_) {
        const float s = (part[0][tid] + part[1][tid] + part[2][tid] + part[3][tid]) * inv;
        o[(size_t)r * H_ + h * HD_ + tid] = s;
    }
}

// ---------------------------------------------------------------------------
// h = silu(g) * u, in place on g. float4 grid-stride.
// ---------------------------------------------------------------------------
__global__ __launch_bounds__(256) void silu_mul_k(
    float* __restrict__ g, const float* __restrict__ u, int n4)
{
    int i = blockIdx.x * blockDim.x + threadIdx.x;
    const int stride = gridDim.x * blockDim.x;
    for (; i < n4; i += stride) {
        float4 gv = ((float4*)g)[i];
        const float4 uv = ((const float4*)u)[i];
        gv.x = gv.x / (1.f + __expf(-gv.x)) * uv.x;
        gv.y = gv.y / (1.f + __expf(-gv.y)) * uv.y;
        gv.z = gv.z / (1.f + __expf(-gv.z)) * uv.z;
        gv.w = gv.w / (1.f + __expf(-gv.w)) * uv.w;
        ((float4*)g)[i] = gv;
    }
}

// ---------------------------------------------------------------------------
extern "C" void kernel_launch(void* const* d_in, const int* in_sizes, int n_in,
                              void* d_out, int out_size, void* d_ws, size_t ws_size,
                              hipStream_t stream)
{
    (void)in_sizes; (void)n_in; (void)out_size; (void)ws_size;

    const float* hidden      = (const float*)d_in[0];   // (S, H)
    const float* comp_w      = (const float*)d_in[1];   // (COMP, S)
    const float* comp_b      = (const float*)d_in[2];   // (COMP,)
    const float* q_w         = (const float*)d_in[3];   // (H, H)
    const float* k_w         = (const float*)d_in[4];   // (KV, H)
    const float* v_w         = (const float*)d_in[5];   // (KV, H)
    const float* o_w         = (const float*)d_in[6];   // (H, H)
    const float* attn_norm_w = (const float*)d_in[7];   // (H,)
    const float* mlp_norm_w  = (const float*)d_in[8];   // (H,)
    const float* gate_w      = (const float*)d_in[9];   // (FF, H)
    const float* up_w        = (const float*)d_in[10];  // (FF, H)
    const float* down_w      = (const float*)d_in[11];  // (H, FF)
    float* out = (float*)d_out;                         // (COMP, H)

    // Workspace layout (floats); total ~27.3M floats = ~109 MB
    float* w = (float*)d_ws;
    float* comp0 = w; w += (size_t)COMP_ * H_;
    float* comp1 = w; w += (size_t)COMP_ * H_;
    float* ct    = w; w += (size_t)COMP_ * H_;
    float* ct2   = w; w += (size_t)COMP_ * H_;
    float* qb    = w; w += (size_t)COMP_ * H_;
    float* ob    = w; w += (size_t)COMP_ * H_;
    float* kb    = w; w += (size_t)TOT_ * KV_;
    float* vb    = w; w += (size_t)TOT_ * KV_;
    float* gb    = w; w += (size_t)COMP_ * FF_;
    float* ub    = w; w += (size_t)COMP_ * FF_;

    const dim3 blk(256);

    // compressed = comp_w @ hidden + comp_b   (NN GEMM; bias per output row)
    gemm64<false><<<dim3(H_ / 64, COMP_ / 64), blk, 0, stream>>>(
        comp_w, hidden, nullptr, comp_b, comp0, COMP_, H_, S_);

    float* cur = comp0;
    for (int d = 0; d < 2; d++) {
        // ct = rmsnorm(compressed, attn_norm_w)
        rmsnorm_k<<<COMP_, blk, 0, stream>>>(cur, attn_norm_w, ct);

        // q = ct @ q_w^T
        gemm64<true><<<dim3(H_ / 64, COMP_ / 64), blk, 0, stream>>>(
            ct, q_w, nullptr, nullptr, qb, COMP_, H_, H_);

        // k = [hidden; compressed] @ k_w^T  (two calls, no concat copy)
        gemm64<true><<<dim3(KV_ / 64, S_ / 64), blk, 0, stream>>>(
            hidden, k_w, nullptr, nullptr, kb, S_, KV_, H_);
        gemm64<true><<<dim3(KV_ / 64, COMP_ / 64), blk, 0, stream>>>(
            cur, k_w, nullptr, nullptr, kb + (size_t)S_ * KV_, COMP_, KV_, H_);

        // v likewise
        gemm64<true><<<dim3(KV_ / 64, S_ / 64), blk, 0, stream>>>(
            hidden, v_w, nullptr, nullptr, vb, S_, KV_, H_);
        gemm64<true><<<dim3(KV_ / 64, COMP_ / 64), blk, 0, stream>>>(
            cur, v_w, nullptr, nullptr, vb + (size_t)S_ * KV_, COMP_, KV_, H_);

        // attention
        attn_k<<<dim3(COMP_, NH_), blk, 0, stream>>>(qb, kb, vb, ob);

        // compressed = o @ o_w^T + ct
        gemm64<true><<<dim3(H_ / 64, COMP_ / 64), blk, 0, stream>>>(
            ob, o_w, ct, nullptr, comp1, COMP_, H_, H_);

        // ct2 = rmsnorm(compressed, mlp_norm_w)
        rmsnorm_k<<<COMP_, blk, 0, stream>>>(comp1, mlp_norm_w, ct2);

        // gate / up
        gemm64<true><<<dim3(FF_ / 64, COMP_ / 64), blk, 0, stream>>>(
            ct2, gate_w, nullptr, nullptr, gb, COMP_, FF_, H_);
        gemm64<true><<<dim3(FF_ / 64, COMP_ / 64), blk, 0, stream>>>(
            ct2, up_w, nullptr, nullptr, ub, COMP_, FF_, H_);

        // g = silu(g) * u
        silu_mul_k<<<2048, blk, 0, stream>>>(gb, ub, COMP_ * FF_ / 4);

        // compressed = g @ down_w^T + ct2  (last depth writes d_out directly)
        float* dst = (d == 1) ? out : comp1 == comp0 ? comp1 : comp0;
        gemm64<true><<<dim3(H_ / 64, COMP_ / 64), blk, 0, stream>>>(
            gb, down_w, ct2, nullptr, dst, COMP_, H_, FF_);
        cur = dst;
    }
}

// Round 2
// 4789.233 us; speedup vs baseline: 2.3933x; 2.3933x over previous
//
#include <hip/hip_runtime.h>
#include <math.h>

// Problem constants (Compress_30047591202836)
constexpr int S_   = 2048;
constexpr int H_   = 2048;
constexpr int NH_  = 32;
constexpr int NKV_ = 8;
constexpr int HD_  = 64;
constexpr int GROUPS_ = NH_ / NKV_;     // 4
constexpr int KV_  = NKV_ * HD_;        // 512
constexpr int COMP_ = 1024;             // S * 0.5
constexpr int FF_  = 5632;
constexpr int TOT_ = S_ + COMP_;        // 3072
constexpr float EPS_ = 1e-6f;

// ---------------------------------------------------------------------------
// Generic fp32 GEMM:  C[M,N] = A[M,K] @ B + (bias per row) + (addp elementwise)
//   BT=true : B is (N,K) row-major  (C = A @ B^T — all weight matmuls)
//   BT=false: B is (K,N) row-major  (C = A @ B   — the compression matmul)
// Tile 64x64, BK=16, 256 threads, 4x4 accumulators per thread.
// ---------------------------------------------------------------------------
template <bool BT>
__global__ __launch_bounds__(256) void gemm64(
    const float* __restrict__ A, const float* __restrict__ Bm,
    const float* __restrict__ addp, const float* __restrict__ bias,
    float* __restrict__ C, int M, int N, int K)
{
    __shared__ float As[16][68];
    __shared__ float Bs[16][68];

    const int tid = threadIdx.x;
    const int bm = blockIdx.y, bn = blockIdx.x;
    const int tx = tid & 15, ty = tid >> 4;

    const int lr = tid >> 2;
    const int lk = (tid & 3) << 2;
    const int bkr = tid >> 4;
    const int bkc = (tid & 15) << 2;

    float acc[4][4] = {};

    for (int k0 = 0; k0 < K; k0 += 16) {
        float4 av = *(const float4*)&A[(size_t)(bm * 64 + lr) * K + k0 + lk];
        float4 bv;
        if (BT) {
            bv = *(const float4*)&Bm[(size_t)(bn * 64 + lr) * K + k0 + lk];
        } else {
            bv = *(const float4*)&Bm[(size_t)(k0 + bkr) * N + bn * 64 + bkc];
        }
        __syncthreads();
        As[lk + 0][lr] = av.x;
        As[lk + 1][lr] = av.y;
        As[lk + 2][lr] = av.z;
        As[lk + 3][lr] = av.w;
        if (BT) {
            Bs[lk + 0][lr] = bv.x;
            Bs[lk + 1][lr] = bv.y;
            Bs[lk + 2][lr] = bv.z;
            Bs[lk + 3][lr] = bv.w;
        } else {
            *(float4*)&Bs[bkr][bkc] = bv;
        }
        __syncthreads();

#pragma unroll
        for (int kk = 0; kk < 16; kk++) {
            float4 a = *(float4*)&As[kk][ty * 4];
            float4 b = *(float4*)&Bs[kk][tx * 4];
            float ar[4] = {a.x, a.y, a.z, a.w};
            float br[4] = {b.x, b.y, b.z, b.w};
#pragma unroll
            for (int i = 0; i < 4; i++)
#pragma unroll
                for (int j = 0; j < 4; j++)
                    acc[i][j] = fmaf(ar[i], br[j], acc[i][j]);
        }
    }

#pragma unroll
    for (int i = 0; i < 4; i++) {
        const int row = bm * 64 + ty * 4 + i;
        const int col = bn * 64 + tx * 4;
        float4 r = {acc[i][0], acc[i][1], acc[i][2], acc[i][3]};
        if (bias) {
            const float bb = bias[row];
            r.x += bb; r.y += bb; r.z += bb; r.w += bb;
        }
        if (addp) {
            float4 ad = *(const float4*)&addp[(size_t)row * N + col];
            r.x += ad.x; r.y += ad.y; r.z += ad.z; r.w += ad.w;
        }
        *(float4*)&C[(size_t)row * N + col] = r;
    }
}

// ---------------------------------------------------------------------------
// RMSNorm over rows of length H_=2048. One block (256 threads) per row.
// ---------------------------------------------------------------------------
__global__ __launch_bounds__(256) void rmsnorm_k(
    const float* __restrict__ x, const float* __restrict__ w,
    float* __restrict__ y)
{
    const int row = blockIdx.x;
    const float* xr = x + (size_t)row * H_;
    __shared__ float red[256];

    float s = 0.f;
#pragma unroll
    for (int i = 0; i < 8; i++) {
        const float v = xr[threadIdx.x + i * 256];
        s += v * v;
    }
    red[threadIdx.x] = s;
    __syncthreads();
    for (int t = 128; t > 0; t >>= 1) {
        if (threadIdx.x < t) red[threadIdx.x] += red[threadIdx.x + t];
        __syncthreads();
    }
    const float scale = rsqrtf(red[0] * (1.0f / H_) + EPS_);
#pragma unroll
    for (int i = 0; i < 8; i++) {
        const int idx = threadIdx.x + i * 256;
        y[(size_t)row * H_ + idx] = xr[idx] * scale * w[idx];
    }
}

// ---------------------------------------------------------------------------
// Flash-style GQA attention. One block per (64-row Q tile, head).
// K/V staged in LDS 64x64 tiles (coalesced); scores via gemm64-style 4x4
// register tiling; online softmax with __shfl_xor over 16-lane row groups;
// P tile through LDS for the PV matmul.
//   q: (COMP_, H_)   k,v: (TOT_, KV_)   o: (COMP_, H_)
// LDS: 4 * 64*68*4B = 69.6 KB -> 2 blocks/CU. Grid 16x32 = 512 blocks.
// ---------------------------------------------------------------------------
__global__ __launch_bounds__(256) void attn_flash(
    const float* __restrict__ q, const float* __restrict__ k,
    const float* __restrict__ v, float* __restrict__ o)
{
    const int qt  = blockIdx.x;       // q tile 0..15
    const int h   = blockIdx.y;       // head 0..31
    const int kvh = h / GROUPS_;
    const int tid = threadIdx.x;
    const int tx = tid & 15, ty = tid >> 4;

    __shared__ float Qs[HD_][68];     // [dim][row], pre-scaled by 1/8
    __shared__ float Ks[HD_][68];     // [dim][key]
    __shared__ float Vs[64][68];      // [key][dim]
    __shared__ float Ps[64][68];      // [key][row]

    const int q0 = qt * 64;

    // Stage Q tile transposed, fused 1/sqrt(HD) scale
#pragma unroll
    for (int p = 0; p < 4; p++) {
        const int idx = p * 256 + tid;
        const int row = idx >> 4;
        const int d0  = (idx & 15) << 2;
        float4 qv = *(const float4*)&q[(size_t)(q0 + row) * H_ + h * HD_ + d0];
        Qs[d0 + 0][row] = qv.x * 0.125f;
        Qs[d0 + 1][row] = qv.y * 0.125f;
        Qs[d0 + 2][row] = qv.z * 0.125f;
        Qs[d0 + 3][row] = qv.w * 0.125f;
    }

    float m[4], l[4] = {0.f, 0.f, 0.f, 0.f};
    float acc[4][4] = {};
#pragma unroll
    for (int i = 0; i < 4; i++) m[i] = -1e30f;

    for (int t0 = 0; t0 < TOT_; t0 += 64) {
        __syncthreads();   // prev PV done (Ps/Vs/Ks reusable); Qs visible (1st iter)
        // Stage K tile transposed + V tile direct (both coalesced from global)
#pragma unroll
        for (int p = 0; p < 4; p++) {
            const int idx = p * 256 + tid;
            const int key = idx >> 4;
            const int d0  = (idx & 15) << 2;
            const size_t gofs = (size_t)(t0 + key) * KV_ + kvh * HD_ + d0;
            float4 kv4 = *(const float4*)&k[gofs];
            float4 vv4 = *(const float4*)&v[gofs];
            Ks[d0 + 0][key] = kv4.x;
            Ks[d0 + 1][key] = kv4.y;
            Ks[d0 + 2][key] = kv4.z;
            Ks[d0 + 3][key] = kv4.w;
            *(float4*)&Vs[key][d0] = vv4;
        }
        __syncthreads();

        // Scores: s[i][j] = sum_d Qs[d][ty*4+i] * Ks[d][tx*4+j]
        float s[4][4] = {};
#pragma unroll
        for (int d = 0; d < HD_; d++) {
            float4 a = *(float4*)&Qs[d][ty * 4];
            float4 b = *(float4*)&Ks[d][tx * 4];
            float ar[4] = {a.x, a.y, a.z, a.w};
            float br[4] = {b.x, b.y, b.z, b.w};
#pragma unroll
            for (int i = 0; i < 4; i++)
#pragma unroll
                for (int j = 0; j < 4; j++)
                    s[i][j] = fmaf(ar[i], br[j], s[i][j]);
        }

        // Online softmax: row stats across the 16 lanes sharing ty
        float alpha[4], rs[4];
#pragma unroll
        for (int i = 0; i < 4; i++) {
            float mt = fmaxf(fmaxf(s[i][0], s[i][1]), fmaxf(s[i][2], s[i][3]));
#pragma unroll
            for (int msk = 1; msk < 16; msk <<= 1)
                mt = fmaxf(mt, __shfl_xor(mt, msk, 16));
            const float mn = fmaxf(m[i], mt);
            alpha[i] = __expf(m[i] - mn);
            m[i] = mn;
            float ss = 0.f;
#pragma unroll
            for (int j = 0; j < 4; j++) {
                const float p = __expf(s[i][j] - mn);
                s[i][j] = p;
                ss += p;
            }
#pragma unroll
            for (int msk = 1; msk < 16; msk <<= 1)
                ss += __shfl_xor(ss, msk, 16);
            rs[i] = ss;
        }
#pragma unroll
        for (int i = 0; i < 4; i++) l[i] = l[i] * alpha[i] + rs[i];

        // P -> LDS as [key][row] for the PV matmul
#pragma unroll
        for (int i = 0; i < 4; i++)
#pragma unroll
            for (int j = 0; j < 4; j++)
                Ps[tx * 4 + j][ty * 4 + i] = s[i][j];
        __syncthreads();

        // Rescale O, then acc[i][j] += sum_key Ps[key][ty*4+i] * Vs[key][tx*4+j]
#pragma unroll
        for (int i = 0; i < 4; i++)
#pragma unroll
            for (int j = 0; j < 4; j++)
                acc[i][j] *= alpha[i];
#pragma unroll
        for (int kk = 0; kk < 64; kk++) {
            float4 pv = *(float4*)&Ps[kk][ty * 4];
            float4 vv = *(float4*)&Vs[kk][tx * 4];
            float pr[4] = {pv.x, pv.y, pv.z, pv.w};
            float vr[4] = {vv.x, vv.y, vv.z, vv.w};
#pragma unroll
            for (int i = 0; i < 4; i++)
#pragma unroll
                for (int j = 0; j < 4; j++)
                    acc[i][j] = fmaf(pr[i], vr[j], acc[i][j]);
        }
    }

    // Epilogue: divide by softmax denom, store
#pragma unroll
    for (int i = 0; i < 4; i++) {
        const float inv = 1.0f / l[i];
        float4 r = {acc[i][0] * inv, acc[i][1] * inv, acc[i][2] * inv, acc[i][3] * inv};
        *(float4*)&o[(size_t)(q0 + ty * 4 + i) * H_ + h * HD_ + tx * 4] = r;
    }
}

// ---------------------------------------------------------------------------
// h = silu(g) * u, in place on g. float4 grid-stride.
// ---------------------------------------------------------------------------
__global__ __launch_bounds__(256) void silu_mul_k(
    float* __restrict__ g, const float* __restrict__ u, int n4)
{
    int i = blockIdx.x * blockDim.x + threadIdx.x;
    const int stride = gridDim.x * blockDim.x;
    for (; i < n4; i += stride) {
        float4 gv = ((float4*)g)[i];
        const float4 uv = ((const float4*)u)[i];
        gv.x = gv.x / (1.f + __expf(-gv.x)) * uv.x;
        gv.y = gv.y / (1.f + __expf(-gv.y)) * uv.y;
        gv.z = gv.z / (1.f + __expf(-gv.z)) * uv.z;
        gv.w = gv.w / (1.f + __expf(-gv.w)) * uv.w;
        ((float4*)g)[i] = gv;
    }
}

// ---------------------------------------------------------------------------
extern "C" void kernel_launch(void* const* d_in, const int* in_sizes, int n_in,
                              void* d_out, int out_size, void* d_ws, size_t ws_size,
                              hipStream_t stream)
{
    (void)in_sizes; (void)n_in; (void)out_size; (void)ws_size;

    const float* hidden      = (const float*)d_in[0];   // (S, H)
    const float* comp_w      = (const float*)d_in[1];   // (COMP, S)
    const float* comp_b      = (const float*)d_in[2];   // (COMP,)
    const float* q_w         = (const float*)d_in[3];   // (H, H)
    const float* k_w         = (const float*)d_in[4];   // (KV, H)
    const float* v_w         = (const float*)d_in[5];   // (KV, H)
    const float* o_w         = (const float*)d_in[6];   // (H, H)
    const float* attn_norm_w = (const float*)d_in[7];   // (H,)
    const float* mlp_norm_w  = (const float*)d_in[8];   // (H,)
    const float* gate_w      = (const float*)d_in[9];   // (FF, H)
    const float* up_w        = (const float*)d_in[10];  // (FF, H)
    const float* down_w      = (const float*)d_in[11];  // (H, FF)
    float* out = (float*)d_out;                         // (COMP, H)

    float* w = (float*)d_ws;
    float* comp0 = w; w += (size_t)COMP_ * H_;
    float* comp1 = w; w += (size_t)COMP_ * H_;
    float* ct    = w; w += (size_t)COMP_ * H_;
    float* ct2   = w; w += (size_t)COMP_ * H_;
    float* qb    = w; w += (size_t)COMP_ * H_;
    float* ob    = w; w += (size_t)COMP_ * H_;
    float* kb    = w; w += (size_t)TOT_ * KV_;
    float* vb    = w; w += (size_t)TOT_ * KV_;
    float* gb    = w; w += (size_t)COMP_ * FF_;
    float* ub    = w; w += (size_t)COMP_ * FF_;

    const dim3 blk(256);

    // compressed = comp_w @ hidden + comp_b
    gemm64<false><<<dim3(H_ / 64, COMP_ / 64), blk, 0, stream>>>(
        comp_w, hidden, nullptr, comp_b, comp0, COMP_, H_, S_);

    float* cur = comp0;
    for (int d = 0; d < 2; d++) {
        rmsnorm_k<<<COMP_, blk, 0, stream>>>(cur, attn_norm_w, ct);

        // q = ct @ q_w^T
        gemm64<true><<<dim3(H_ / 64, COMP_ / 64), blk, 0, stream>>>(
            ct, q_w, nullptr, nullptr, qb, COMP_, H_, H_);

        // k = [hidden; compressed] @ k_w^T
        gemm64<true><<<dim3(KV_ / 64, S_ / 64), blk, 0, stream>>>(
            hidden, k_w, nullptr, nullptr, kb, S_, KV_, H_);
        gemm64<true><<<dim3(KV_ / 64, COMP_ / 64), blk, 0, stream>>>(
            cur, k_w, nullptr, nullptr, kb + (size_t)S_ * KV_, COMP_, KV_, H_);

        // v likewise
        gemm64<true><<<dim3(KV_ / 64, S_ / 64), blk, 0, stream>>>(
            hidden, v_w, nullptr, nullptr, vb, S_, KV_, H_);
        gemm64<true><<<dim3(KV_ / 64, COMP_ / 64), blk, 0, stream>>>(
            cur, v_w, nullptr, nullptr, vb + (size_t)S_ * KV_, COMP_, KV_, H_);

        // attention (flash-style, tiled)
        attn_flash<<<dim3(COMP_ / 64, NH_), blk, 0, stream>>>(qb, kb, vb, ob);

        // compressed = o @ o_w^T + ct
        gemm64<true><<<dim3(H_ / 64, COMP_ / 64), blk, 0, stream>>>(
            ob, o_w, ct, nullptr, comp1, COMP_, H_, H_);

        rmsnorm_k<<<COMP_, blk, 0, stream>>>(comp1, mlp_norm_w, ct2);

        // gate / up
        gemm64<true><<<dim3(FF_ / 64, COMP_ / 64), blk, 0, stream>>>(
            ct2, gate_w, nullptr, nullptr, gb, COMP_, FF_, H_);
        gemm64<true><<<dim3(FF_ / 64, COMP_ / 64), blk, 0, stream>>>(
            ct2, up_w, nullptr, nullptr, ub, COMP_, FF_, H_);

        silu_mul_k<<<2048, blk, 0, stream>>>(gb, ub, COMP_ * FF_ / 4);

        // compressed = g @ down_w^T + ct2
        float* dst = (d == 1) ? out : comp1 == comp0 ? comp1 : comp0;
        gemm64<true><<<dim3(H_ / 64, COMP_ / 64), blk, 0, stream>>>(
            gb, down_w, ct2, nullptr, dst, COMP_, H_, FF_);
        cur = dst;
    }
}

// Round 3
// 2638.101 us; speedup vs baseline: 4.3448x; 1.8154x over previous
//
#include <hip/hip_runtime.h>
#include <math.h>

// Problem constants (Compress_30047591202836)
constexpr int S_   = 2048;
constexpr int H_   = 2048;
constexpr int NH_  = 32;
constexpr int NKV_ = 8;
constexpr int HD_  = 64;
constexpr int GROUPS_ = NH_ / NKV_;     // 4
constexpr int KV_  = NKV_ * HD_;        // 512
constexpr int COMP_ = 1024;             // S * 0.5
constexpr int FF_  = 5632;
constexpr int TOT_ = S_ + COMP_;        // 3072
constexpr float EPS_ = 1e-6f;

typedef __attribute__((ext_vector_type(4))) float f32x4;
typedef __attribute__((ext_vector_type(8))) short bf16x8;

__device__ __forceinline__ ushort f2bf(float x) {
    union { float f; unsigned u; } v; v.f = x;
    unsigned r = v.u + 0x7fffu + ((v.u >> 16) & 1u);   // RNE
    return (ushort)(r >> 16);
}
__device__ __forceinline__ float bf2f(ushort x) {
    union { unsigned u; float f; } v; v.u = ((unsigned)x) << 16;
    return v.f;
}

// ---------------------------------------------------------------------------
// fp32 -> bf16 convert, float4/ushort4 grid-stride. n4 = n/4.
// ---------------------------------------------------------------------------
__global__ __launch_bounds__(256) void f2b_k(
    const float* __restrict__ x, ushort* __restrict__ y, int n4)
{
    int i = blockIdx.x * 256 + threadIdx.x;
    const int stride = gridDim.x * 256;
    for (; i < n4; i += stride) {
        float4 v = ((const float4*)x)[i];
        ushort4 r = {f2bf(v.x), f2bf(v.y), f2bf(v.z), f2bf(v.w)};
        ((ushort4*)y)[i] = r;
    }
}

// ---------------------------------------------------------------------------
// bf16 MFMA GEMM:  C[M,N] = A[M,K] @ B[N,K]^T (+ fp32 addp), A,B bf16.
// Outputs: optional fp32 outf, optional bf16 outb (either may be null).
// 128x128 tile, BK=32, 256 threads = 4 waves, each wave 64x64 via 4x4
// mfma_f32_16x16x32_bf16. Staging via global_load_lds width=16 (m97).
// Requires M%128==0, N%128==0, K%32==0.
// Fragment layouts (m89/m91-verified): A/B frag: [idx=lane&15][k=quad*8+j];
// C/D: col=lane&15, row=quad*4+reg.
// ---------------------------------------------------------------------------
__global__ __launch_bounds__(256) void mfma_gemm(
    const ushort* __restrict__ A, const ushort* __restrict__ B,
    const float* __restrict__ addp, float* __restrict__ outf,
    ushort* __restrict__ outb, int M, int N, int K)
{
    __shared__ ushort Alds[128 * 32];   // 8 KB
    __shared__ ushort Blds[128 * 32];   // 8 KB

    const int tid  = threadIdx.x;
    const int w    = tid >> 6;
    const int lane = tid & 63;
    const int bm = blockIdx.y, bn = blockIdx.x;
    const int wr = w >> 1, wc = w & 1;          // wave quadrant
    const int fr = lane & 15;                   // fragment row/col
    const int fq = lane >> 4;                   // quad 0..3

    // staging indices: slot covers 16 rows x 32 cols; lane -> (row, k-group)
    const int srow = lane >> 2;                 // 0..15
    const int skof = (lane & 3) * 8;            // 0,8,16,24

    f32x4 acc[4][4];
#pragma unroll
    for (int i = 0; i < 4; i++)
#pragma unroll
        for (int j = 0; j < 4; j++)
            acc[i][j] = (f32x4){0.f, 0.f, 0.f, 0.f};

    for (int k0 = 0; k0 < K; k0 += 32) {
        __syncthreads();   // all waves done reading prev tile
#pragma unroll
        for (int i = 0; i < 2; i++) {
            const int slot = w * 2 + i;         // 0..7
            const ushort* ga = &A[(size_t)(bm * 128 + slot * 16 + srow) * K + k0 + skof];
            __builtin_amdgcn_global_load_lds(
                (const __attribute__((address_space(1))) void*)ga,
                (__attribute__((address_space(3))) void*)&Alds[slot * 512], 16, 0, 0);
            const ushort* gb = &B[(size_t)(bn * 128 + slot * 16 + srow) * K + k0 + skof];
            __builtin_amdgcn_global_load_lds(
                (const __attribute__((address_space(1))) void*)gb,
                (__attribute__((address_space(3))) void*)&Blds[slot * 512], 16, 0, 0);
        }
        __syncthreads();   // vmcnt(0) drained by compiler before barrier

        bf16x8 a[4], b[4];
#pragma unroll
        for (int mt = 0; mt < 4; mt++)
            a[mt] = *(const bf16x8*)&Alds[(wr * 64 + mt * 16 + fr) * 32 + fq * 8];
#pragma unroll
        for (int nt = 0; nt < 4; nt++)
            b[nt] = *(const bf16x8*)&Blds[(wc * 64 + nt * 16 + fr) * 32 + fq * 8];

#pragma unroll
        for (int mt = 0; mt < 4; mt++)
#pragma unroll
            for (int nt = 0; nt < 4; nt++)
                acc[mt][nt] = __builtin_amdgcn_mfma_f32_16x16x32_bf16(
                    a[mt], b[nt], acc[mt][nt], 0, 0, 0);
    }

#pragma unroll
    for (int mt = 0; mt < 4; mt++) {
#pragma unroll
        for (int nt = 0; nt < 4; nt++) {
#pragma unroll
            for (int r = 0; r < 4; r++) {
                const int row = bm * 128 + wr * 64 + mt * 16 + fq * 4 + r;
                const int col = bn * 128 + wc * 64 + nt * 16 + fr;
                float v = acc[mt][nt][r];
                if (addp) v += addp[(size_t)row * N + col];
                if (outf) outf[(size_t)row * N + col] = v;
                if (outb) outb[(size_t)row * N + col] = f2bf(v);
            }
        }
    }
}

// ---------------------------------------------------------------------------
// fp32 GEMM (NN), used only for the compression matmul:
//   C[M,N] = A[M,K] @ B[K,N] + bias per row
// ---------------------------------------------------------------------------
__global__ __launch_bounds__(256) void gemm64_nn(
    const float* __restrict__ A, const float* __restrict__ Bm,
    const float* __restrict__ bias, float* __restrict__ C,
    int M, int N, int K)
{
    __shared__ float As[16][68];
    __shared__ float Bs[16][68];

    const int tid = threadIdx.x;
    const int bm = blockIdx.y, bn = blockIdx.x;
    const int tx = tid & 15, ty = tid >> 4;

    const int lr = tid >> 2;
    const int lk = (tid & 3) << 2;
    const int bkr = tid >> 4;
    const int bkc = (tid & 15) << 2;

    float acc[4][4] = {};

    for (int k0 = 0; k0 < K; k0 += 16) {
        float4 av = *(const float4*)&A[(size_t)(bm * 64 + lr) * K + k0 + lk];
        float4 bv = *(const float4*)&Bm[(size_t)(k0 + bkr) * N + bn * 64 + bkc];
        __syncthreads();
        As[lk + 0][lr] = av.x;
        As[lk + 1][lr] = av.y;
        As[lk + 2][lr] = av.z;
        As[lk + 3][lr] = av.w;
        *(float4*)&Bs[bkr][bkc] = bv;
        __syncthreads();

#pragma unroll
        for (int kk = 0; kk < 16; kk++) {
            float4 a = *(float4*)&As[kk][ty * 4];
            float4 b = *(float4*)&Bs[kk][tx * 4];
            float ar[4] = {a.x, a.y, a.z, a.w};
            float br[4] = {b.x, b.y, b.z, b.w};
#pragma unroll
            for (int i = 0; i < 4; i++)
#pragma unroll
                for (int j = 0; j < 4; j++)
                    acc[i][j] = fmaf(ar[i], br[j], acc[i][j]);
        }
    }

#pragma unroll
    for (int i = 0; i < 4; i++) {
        const int row = bm * 64 + ty * 4 + i;
        const int col = bn * 64 + tx * 4;
        float4 r = {acc[i][0], acc[i][1], acc[i][2], acc[i][3]};
        const float bb = bias[row];
        r.x += bb; r.y += bb; r.z += bb; r.w += bb;
        *(float4*)&C[(size_t)row * N + col] = r;
    }
}

// ---------------------------------------------------------------------------
// RMSNorm, dual fp32 + bf16 output. One block (256 threads) per row.
// ---------------------------------------------------------------------------
__global__ __launch_bounds__(256) void rmsnorm_dual_k(
    const float* __restrict__ x, const float* __restrict__ w,
    float* __restrict__ y, ushort* __restrict__ yb)
{
    const int row = blockIdx.x;
    const float* xr = x + (size_t)row * H_;
    __shared__ float red[256];

    float s = 0.f;
#pragma unroll
    for (int i = 0; i < 8; i++) {
        const float v = xr[threadIdx.x + i * 256];
        s += v * v;
    }
    red[threadIdx.x] = s;
    __syncthreads();
    for (int t = 128; t > 0; t >>= 1) {
        if (threadIdx.x < t) red[threadIdx.x] += red[threadIdx.x + t];
        __syncthreads();
    }
    const float scale = rsqrtf(red[0] * (1.0f / H_) + EPS_);
#pragma unroll
    for (int i = 0; i < 8; i++) {
        const int idx = threadIdx.x + i * 256;
        const float v = xr[idx] * scale * w[idx];
        y[(size_t)row * H_ + idx] = v;
        yb[(size_t)row * H_ + idx] = f2bf(v);
    }
}

// ---------------------------------------------------------------------------
// Flash-style GQA attention (fp32 q/k/v in, bf16 o out).
// ---------------------------------------------------------------------------
__global__ __launch_bounds__(256) void attn_flash(
    const float* __restrict__ q, const float* __restrict__ k,
    const float* __restrict__ v, ushort* __restrict__ o)
{
    const int qt  = blockIdx.x;
    const int h   = blockIdx.y;
    const int kvh = h / GROUPS_;
    const int tid = threadIdx.x;
    const int tx = tid & 15, ty = tid >> 4;

    __shared__ float Qs[HD_][68];
    __shared__ float Ks[HD_][68];
    __shared__ float Vs[64][68];
    __shared__ float Ps[64][68];

    const int q0 = qt * 64;

#pragma unroll
    for (int p = 0; p < 4; p++) {
        const int idx = p * 256 + tid;
        const int row = idx >> 4;
        const int d0  = (idx & 15) << 2;
        float4 qv = *(const float4*)&q[(size_t)(q0 + row) * H_ + h * HD_ + d0];
        Qs[d0 + 0][row] = qv.x * 0.125f;
        Qs[d0 + 1][row] = qv.y * 0.125f;
        Qs[d0 + 2][row] = qv.z * 0.125f;
        Qs[d0 + 3][row] = qv.w * 0.125f;
    }

    float m[4], l[4] = {0.f, 0.f, 0.f, 0.f};
    float acc[4][4] = {};
#pragma unroll
    for (int i = 0; i < 4; i++) m[i] = -1e30f;

    for (int t0 = 0; t0 < TOT_; t0 += 64) {
        __syncthreads();
#pragma unroll
        for (int p = 0; p < 4; p++) {
            const int idx = p * 256 + tid;
            const int key = idx >> 4;
            const int d0  = (idx & 15) << 2;
            const size_t gofs = (size_t)(t0 + key) * KV_ + kvh * HD_ + d0;
            float4 kv4 = *(const float4*)&k[gofs];
            float4 vv4 = *(const float4*)&v[gofs];
            Ks[d0 + 0][key] = kv4.x;
            Ks[d0 + 1][key] = kv4.y;
            Ks[d0 + 2][key] = kv4.z;
            Ks[d0 + 3][key] = kv4.w;
            *(float4*)&Vs[key][d0] = vv4;
        }
        __syncthreads();

        float s[4][4] = {};
#pragma unroll
        for (int d = 0; d < HD_; d++) {
            float4 a = *(float4*)&Qs[d][ty * 4];
            float4 b = *(float4*)&Ks[d][tx * 4];
            float ar[4] = {a.x, a.y, a.z, a.w};
            float br[4] = {b.x, b.y, b.z, b.w};
#pragma unroll
            for (int i = 0; i < 4; i++)
#pragma unroll
                for (int j = 0; j < 4; j++)
                    s[i][j] = fmaf(ar[i], br[j], s[i][j]);
        }

        float alpha[4], rs[4];
#pragma unroll
        for (int i = 0; i < 4; i++) {
            float mt = fmaxf(fmaxf(s[i][0], s[i][1]), fmaxf(s[i][2], s[i][3]));
#pragma unroll
            for (int msk = 1; msk < 16; msk <<= 1)
                mt = fmaxf(mt, __shfl_xor(mt, msk, 16));
            const float mn = fmaxf(m[i], mt);
            alpha[i] = __expf(m[i] - mn);
            m[i] = mn;
            float ss = 0.f;
#pragma unroll
            for (int j = 0; j < 4; j++) {
                const float p = __expf(s[i][j] - mn);
                s[i][j] = p;
                ss += p;
            }
#pragma unroll
            for (int msk = 1; msk < 16; msk <<= 1)
                ss += __shfl_xor(ss, msk, 16);
            rs[i] = ss;
        }
#pragma unroll
        for (int i = 0; i < 4; i++) l[i] = l[i] * alpha[i] + rs[i];

#pragma unroll
        for (int i = 0; i < 4; i++)
#pragma unroll
            for (int j = 0; j < 4; j++)
                Ps[tx * 4 + j][ty * 4 + i] = s[i][j];
        __syncthreads();

#pragma unroll
        for (int i = 0; i < 4; i++)
#pragma unroll
            for (int j = 0; j < 4; j++)
                acc[i][j] *= alpha[i];
#pragma unroll
        for (int kk = 0; kk < 64; kk++) {
            float4 pv = *(float4*)&Ps[kk][ty * 4];
            float4 vv = *(float4*)&Vs[kk][tx * 4];
            float pr[4] = {pv.x, pv.y, pv.z, pv.w};
            float vr[4] = {vv.x, vv.y, vv.z, vv.w};
#pragma unroll
            for (int i = 0; i < 4; i++)
#pragma unroll
                for (int j = 0; j < 4; j++)
                    acc[i][j] = fmaf(pr[i], vr[j], acc[i][j]);
        }
    }

#pragma unroll
    for (int i = 0; i < 4; i++) {
        const float inv = 1.0f / l[i];
        ushort4 r = {f2bf(acc[i][0] * inv), f2bf(acc[i][1] * inv),
                     f2bf(acc[i][2] * inv), f2bf(acc[i][3] * inv)};
        *(ushort4*)&o[(size_t)(q0 + ty * 4 + i) * H_ + h * HD_ + tx * 4] = r;
    }
}

// ---------------------------------------------------------------------------
// bf16 silu-mul in place: g = silu(g) * u. n4 = n/4.
// ---------------------------------------------------------------------------
__global__ __launch_bounds__(256) void silu_mul_bf_k(
    ushort* __restrict__ g, const ushort* __restrict__ u, int n4)
{
    int i = blockIdx.x * 256 + threadIdx.x;
    const int stride = gridDim.x * 256;
    for (; i < n4; i += stride) {
        ushort4 gv = ((ushort4*)g)[i];
        ushort4 uv = ((const ushort4*)u)[i];
        float x0 = bf2f(gv.x), x1 = bf2f(gv.y), x2 = bf2f(gv.z), x3 = bf2f(gv.w);
        x0 = x0 / (1.f + __expf(-x0)) * bf2f(uv.x);
        x1 = x1 / (1.f + __expf(-x1)) * bf2f(uv.y);
        x2 = x2 / (1.f + __expf(-x2)) * bf2f(uv.z);
        x3 = x3 / (1.f + __expf(-x3)) * bf2f(uv.w);
        ushort4 r = {f2bf(x0), f2bf(x1), f2bf(x2), f2bf(x3)};
        ((ushort4*)g)[i] = r;
    }
}

// ---------------------------------------------------------------------------
extern "C" void kernel_launch(void* const* d_in, const int* in_sizes, int n_in,
                              void* d_out, int out_size, void* d_ws, size_t ws_size,
                              hipStream_t stream)
{
    (void)in_sizes; (void)n_in; (void)out_size; (void)ws_size;

    const float* hidden      = (const float*)d_in[0];
    const float* comp_w      = (const float*)d_in[1];
    const float* comp_b      = (const float*)d_in[2];
    const float* q_w         = (const float*)d_in[3];
    const float* k_w         = (const float*)d_in[4];
    const float* v_w         = (const float*)d_in[5];
    const float* o_w         = (const float*)d_in[6];
    const float* attn_norm_w = (const float*)d_in[7];
    const float* mlp_norm_w  = (const float*)d_in[8];
    const float* gate_w      = (const float*)d_in[9];
    const float* up_w        = (const float*)d_in[10];
    const float* down_w      = (const float*)d_in[11];
    float* out = (float*)d_out;

    // ---- workspace carve (256B-aligned chunks) ----
    char* p = (char*)d_ws;
    auto alloc = [&](size_t bytes) -> char* {
        char* r = p; p += (bytes + 255) & ~(size_t)255; return r;
    };
    // bf16 weights
    ushort* qw_bf   = (ushort*)alloc((size_t)H_ * H_ * 2);
    ushort* kw_bf   = (ushort*)alloc((size_t)KV_ * H_ * 2);
    ushort* vw_bf   = (ushort*)alloc((size_t)KV_ * H_ * 2);
    ushort* ow_bf   = (ushort*)alloc((size_t)H_ * H_ * 2);
    ushort* gate_bf = (ushort*)alloc((size_t)FF_ * H_ * 2);
    ushort* up_bf   = (ushort*)alloc((size_t)FF_ * H_ * 2);
    ushort* down_bf = (ushort*)alloc((size_t)H_ * FF_ * 2);
    ushort* hid_bf  = (ushort*)alloc((size_t)S_ * H_ * 2);
    // fp32 activations
    float* comp0 = (float*)alloc((size_t)COMP_ * H_ * 4);
    float* comp1 = (float*)alloc((size_t)COMP_ * H_ * 4);
    float* ct    = (float*)alloc((size_t)COMP_ * H_ * 4);
    float* ct2   = (float*)alloc((size_t)COMP_ * H_ * 4);
    float* qb    = (float*)alloc((size_t)COMP_ * H_ * 4);
    float* kb    = (float*)alloc((size_t)TOT_ * KV_ * 4);
    float* vb    = (float*)alloc((size_t)TOT_ * KV_ * 4);
    // bf16 activations
    ushort* ct_bf  = (ushort*)alloc((size_t)COMP_ * H_ * 2);
    ushort* ct2_bf = (ushort*)alloc((size_t)COMP_ * H_ * 2);
    ushort* cur_bf = (ushort*)alloc((size_t)COMP_ * H_ * 2);
    ushort* ob_bf  = (ushort*)alloc((size_t)COMP_ * H_ * 2);
    ushort* gb_bf  = (ushort*)alloc((size_t)COMP_ * FF_ * 2);
    ushort* ub_bf  = (ushort*)alloc((size_t)COMP_ * FF_ * 2);

    const dim3 blk(256);

    // ---- one-time converts (weights + hidden) ----
    f2b_k<<<512, blk, 0, stream>>>(q_w,    qw_bf,   H_ * H_ / 4);
    f2b_k<<<512, blk, 0, stream>>>(k_w,    kw_bf,   KV_ * H_ / 4);
    f2b_k<<<512, blk, 0, stream>>>(v_w,    vw_bf,   KV_ * H_ / 4);
    f2b_k<<<512, blk, 0, stream>>>(o_w,    ow_bf,   H_ * H_ / 4);
    f2b_k<<<512, blk, 0, stream>>>(gate_w, gate_bf, FF_ * H_ / 4);
    f2b_k<<<512, blk, 0, stream>>>(up_w,   up_bf,   FF_ * H_ / 4);
    f2b_k<<<512, blk, 0, stream>>>(down_w, down_bf, H_ * FF_ / 4);
    f2b_k<<<512, blk, 0, stream>>>(hidden, hid_bf,  S_ * H_ / 4);

    // compressed = comp_w @ hidden + comp_b   (fp32 NN)
    gemm64_nn<<<dim3(H_ / 64, COMP_ / 64), blk, 0, stream>>>(
        comp_w, hidden, comp_b, comp0, COMP_, H_, S_);
    f2b_k<<<512, blk, 0, stream>>>(comp0, cur_bf, COMP_ * H_ / 4);

    float* cur = comp0;
    for (int d = 0; d < 2; d++) {
        rmsnorm_dual_k<<<COMP_, blk, 0, stream>>>(cur, attn_norm_w, ct, ct_bf);

        // q = ct @ q_w^T (fp32 out for attention)
        mfma_gemm<<<dim3(H_ / 128, COMP_ / 128), blk, 0, stream>>>(
            ct_bf, qw_bf, nullptr, qb, nullptr, COMP_, H_, H_);

        // k = [hidden; compressed] @ k_w^T
        mfma_gemm<<<dim3(KV_ / 128, S_ / 128), blk, 0, stream>>>(
            hid_bf, kw_bf, nullptr, kb, nullptr, S_, KV_, H_);
        mfma_gemm<<<dim3(KV_ / 128, COMP_ / 128), blk, 0, stream>>>(
            cur_bf, kw_bf, nullptr, kb + (size_t)S_ * KV_, nullptr, COMP_, KV_, H_);

        // v likewise
        mfma_gemm<<<dim3(KV_ / 128, S_ / 128), blk, 0, stream>>>(
            hid_bf, vw_bf, nullptr, vb, nullptr, S_, KV_, H_);
        mfma_gemm<<<dim3(KV_ / 128, COMP_ / 128), blk, 0, stream>>>(
            cur_bf, vw_bf, nullptr, vb + (size_t)S_ * KV_, nullptr, COMP_, KV_, H_);

        // attention (bf16 output for o-proj)
        attn_flash<<<dim3(COMP_ / 64, NH_), blk, 0, stream>>>(qb, kb, vb, ob_bf);

        // compressed = o @ o_w^T + ct
        mfma_gemm<<<dim3(H_ / 128, COMP_ / 128), blk, 0, stream>>>(
            ob_bf, ow_bf, ct, comp1, nullptr, COMP_, H_, H_);

        rmsnorm_dual_k<<<COMP_, blk, 0, stream>>>(comp1, mlp_norm_w, ct2, ct2_bf);

        // gate / up (bf16 outputs only)
        mfma_gemm<<<dim3(FF_ / 128, COMP_ / 128), blk, 0, stream>>>(
            ct2_bf, gate_bf, nullptr, nullptr, gb_bf, COMP_, FF_, H_);
        mfma_gemm<<<dim3(FF_ / 128, COMP_ / 128), blk, 0, stream>>>(
            ct2_bf, up_bf, nullptr, nullptr, ub_bf, COMP_, FF_, H_);

        silu_mul_bf_k<<<1024, blk, 0, stream>>>(gb_bf, ub_bf, COMP_ * FF_ / 4);

        // compressed = g @ down_w^T + ct2
        float* dst = (d == 1) ? out : comp0;
        ushort* dst_bf = (d == 1) ? nullptr : cur_bf;
        mfma_gemm<<<dim3(H_ / 128, COMP_ / 128), blk, 0, stream>>>(
            gb_bf, down_bf, ct2, dst, dst_bf, COMP_, H_, FF_);
        cur = dst;
    }
}

// Round 4
// 1675.961 us; speedup vs baseline: 6.8391x; 1.5741x over previous
//
#include <hip/hip_runtime.h>
#include <math.h>

// Problem constants (Compress_30047591202836)
constexpr int S_   = 2048;
constexpr int H_   = 2048;
constexpr int NH_  = 32;
constexpr int NKV_ = 8;
constexpr int HD_  = 64;
constexpr int GROUPS_ = NH_ / NKV_;     // 4
constexpr int KV_  = NKV_ * HD_;        // 512
constexpr int COMP_ = 1024;             // S * 0.5
constexpr int FF_  = 5632;
constexpr int TOT_ = S_ + COMP_;        // 3072
constexpr float EPS_ = 1e-6f;

typedef __attribute__((ext_vector_type(4))) float f32x4;
typedef __attribute__((ext_vector_type(8))) short bf16x8;
typedef __attribute__((ext_vector_type(8))) ushort u16x8;

__device__ __forceinline__ ushort f2bf(float x) {
    union { float f; unsigned u; } v; v.f = x;
    unsigned r = v.u + 0x7fffu + ((v.u >> 16) & 1u);   // RNE
    return (ushort)(r >> 16);
}
__device__ __forceinline__ float bf2f(ushort x) {
    union { unsigned u; float f; } v; v.u = ((unsigned)x) << 16;
    return v.f;
}

// ---------------------------------------------------------------------------
// fp32 -> bf16 convert, float4/ushort4 grid-stride. n4 = n/4.
// ---------------------------------------------------------------------------
__global__ __launch_bounds__(256) void f2b_k(
    const float* __restrict__ x, ushort* __restrict__ y, int n4)
{
    int i = blockIdx.x * 256 + threadIdx.x;
    const int stride = gridDim.x * 256;
    for (; i < n4; i += stride) {
        float4 v = ((const float4*)x)[i];
        ushort4 r = {f2bf(v.x), f2bf(v.y), f2bf(v.z), f2bf(v.w)};
        ((ushort4*)y)[i] = r;
    }
}

// ---------------------------------------------------------------------------
// bf16 64x64 tiled transpose: out[C][R] = in[R][C]^T. Grid (R/64, C/64).
// Coalesced 32B loads/stores both sides; LDS tile padded to stride 72.
// ---------------------------------------------------------------------------
__global__ __launch_bounds__(256) void tpose64(
    const ushort* __restrict__ in, ushort* __restrict__ out, int R, int C)
{
    __shared__ ushort T[64][72];
    const int r0 = blockIdx.x * 64, c0 = blockIdx.y * 64;
    const int row = threadIdx.x >> 2, seg = threadIdx.x & 3;

    const ushort* g = &in[(size_t)(r0 + row) * C + c0 + seg * 16];
    *(u16x8*)&T[row][seg * 16]     = *(const u16x8*)g;
    *(u16x8*)&T[row][seg * 16 + 8] = *(const u16x8*)(g + 8);
    __syncthreads();

    ushort tmp[16];
#pragma unroll
    for (int j = 0; j < 16; j++) tmp[j] = T[seg * 16 + j][row];
    ushort* go = &out[(size_t)(c0 + row) * R + r0 + seg * 16];
    *(u16x8*)go       = *(const u16x8*)&tmp[0];
    *(u16x8*)(go + 8) = *(const u16x8*)&tmp[8];
}

// ---------------------------------------------------------------------------
// bf16 MFMA GEMM:  C[M,N] = oscale * (A[M,K] @ B[N,K]^T) + bias[row] + addp.
// Outputs: optional fp32 outf, optional bf16 outb.
// 128x128 tile, BK=32, 4 waves, 4x4 mfma_f32_16x16x32_bf16 per wave.
// Staging via global_load_lds width=16 (m97). M%128==0, N%128==0, K%32==0.
// ---------------------------------------------------------------------------
__global__ __launch_bounds__(256) void mfma_gemm(
    const ushort* __restrict__ A, const ushort* __restrict__ B,
    const float* __restrict__ addp, const float* __restrict__ bias,
    float oscale, float* __restrict__ outf, ushort* __restrict__ outb,
    int M, int N, int K)
{
    __shared__ ushort Alds[128 * 32];
    __shared__ ushort Blds[128 * 32];

    const int tid  = threadIdx.x;
    const int w    = tid >> 6;
    const int lane = tid & 63;
    const int bm = blockIdx.y, bn = blockIdx.x;
    const int wr = w >> 1, wc = w & 1;
    const int fr = lane & 15;
    const int fq = lane >> 4;

    const int srow = lane >> 2;
    const int skof = (lane & 3) * 8;

    f32x4 acc[4][4];
#pragma unroll
    for (int i = 0; i < 4; i++)
#pragma unroll
        for (int j = 0; j < 4; j++)
            acc[i][j] = (f32x4){0.f, 0.f, 0.f, 0.f};

    for (int k0 = 0; k0 < K; k0 += 32) {
        __syncthreads();
#pragma unroll
        for (int i = 0; i < 2; i++) {
            const int slot = w * 2 + i;
            const ushort* ga = &A[(size_t)(bm * 128 + slot * 16 + srow) * K + k0 + skof];
            __builtin_amdgcn_global_load_lds(
                (const __attribute__((address_space(1))) void*)ga,
                (__attribute__((address_space(3))) void*)&Alds[slot * 512], 16, 0, 0);
            const ushort* gb = &B[(size_t)(bn * 128 + slot * 16 + srow) * K + k0 + skof];
            __builtin_amdgcn_global_load_lds(
                (const __attribute__((address_space(1))) void*)gb,
                (__attribute__((address_space(3))) void*)&Blds[slot * 512], 16, 0, 0);
        }
        __syncthreads();

        bf16x8 a[4], b[4];
#pragma unroll
        for (int mt = 0; mt < 4; mt++)
            a[mt] = *(const bf16x8*)&Alds[(wr * 64 + mt * 16 + fr) * 32 + fq * 8];
#pragma unroll
        for (int nt = 0; nt < 4; nt++)
            b[nt] = *(const bf16x8*)&Blds[(wc * 64 + nt * 16 + fr) * 32 + fq * 8];

#pragma unroll
        for (int mt = 0; mt < 4; mt++)
#pragma unroll
            for (int nt = 0; nt < 4; nt++)
                acc[mt][nt] = __builtin_amdgcn_mfma_f32_16x16x32_bf16(
                    a[mt], b[nt], acc[mt][nt], 0, 0, 0);
    }

#pragma unroll
    for (int mt = 0; mt < 4; mt++) {
#pragma unroll
        for (int nt = 0; nt < 4; nt++) {
#pragma unroll
            for (int r = 0; r < 4; r++) {
                const int row = bm * 128 + wr * 64 + mt * 16 + fq * 4 + r;
                const int col = bn * 128 + wc * 64 + nt * 16 + fr;
                float v = acc[mt][nt][r] * oscale;
                if (bias) v += bias[row];
                if (addp) v += addp[(size_t)row * N + col];
                if (outf) outf[(size_t)row * N + col] = v;
                if (outb) outb[(size_t)row * N + col] = f2bf(v);
            }
        }
    }
}

// ---------------------------------------------------------------------------
// MFMA flash attention (bf16 in/out, fp32 softmax state).
//   q : (COMP_, H_) bf16, PRE-SCALED by 1/sqrt(HD)
//   k : (TOT_, KV_) bf16 (natural)
//   vt: (KV_, TOT_) bf16 (transposed: vt[kvh*64+dim][t])
//   o : (COMP_, H_) bf16
// Block = (64 q-rows, head); 4 waves x 16 rows; KV tile = 64 keys.
// QK^T and PV via mfma_f32_16x16x32_bf16. P round-trips LDS as bf16.
// All LDS arrays stride 72 (2-way bank aliasing only = free, m136).
// LDS total 36 KB.
// ---------------------------------------------------------------------------
__global__ __launch_bounds__(256) void attn_mfma(
    const ushort* __restrict__ q, const ushort* __restrict__ k,
    const ushort* __restrict__ vt, ushort* __restrict__ o)
{
    constexpr int LDT = 72;
    __shared__ ushort Qs[64 * LDT];
    __shared__ ushort Ks[64 * LDT];
    __shared__ ushort Vs[64 * LDT];
    __shared__ ushort Ps[64 * LDT];

    const int qt = blockIdx.x, h = blockIdx.y;
    const int kvh = h / GROUPS_;
    const int tid = threadIdx.x;
    const int w = tid >> 6, lane = tid & 63;
    const int fr = lane & 15, fq = lane >> 4;
    const int q0 = qt * 64;

    // Stage Q tile (64 rows x 64 dims), coalesced 32B per thread
    {
        const int row = tid >> 2, seg = tid & 3;
        const ushort* g = &q[(size_t)(q0 + row) * H_ + h * HD_ + seg * 16];
        *(u16x8*)&Qs[row * LDT + seg * 16]     = *(const u16x8*)g;
        *(u16x8*)&Qs[row * LDT + seg * 16 + 8] = *(const u16x8*)(g + 8);
    }

    float m[4] = {-1e30f, -1e30f, -1e30f, -1e30f};
    float l[4] = {0.f, 0.f, 0.f, 0.f};
    f32x4 acc[4];
#pragma unroll
    for (int nt = 0; nt < 4; nt++) acc[nt] = (f32x4){0.f, 0.f, 0.f, 0.f};

    for (int t0 = 0; t0 < TOT_; t0 += 64) {
        __syncthreads();   // everyone done with prev Ks/Vs
        {
            const int row = tid >> 2, seg = tid & 3;
            const ushort* gk = &k[(size_t)(t0 + row) * KV_ + kvh * HD_ + seg * 16];
            u16x8 k0v = *(const u16x8*)gk;
            u16x8 k1v = *(const u16x8*)(gk + 8);
            const ushort* gv = &vt[(size_t)(kvh * HD_ + row) * TOT_ + t0 + seg * 16];
            u16x8 v0v = *(const u16x8*)gv;
            u16x8 v1v = *(const u16x8*)(gv + 8);
            *(u16x8*)&Ks[row * LDT + seg * 16]     = k0v;
            *(u16x8*)&Ks[row * LDT + seg * 16 + 8] = k1v;
            *(u16x8*)&Vs[row * LDT + seg * 16]     = v0v;
            *(u16x8*)&Vs[row * LDT + seg * 16 + 8] = v1v;
        }
        __syncthreads();

        // ---- scores: S[16x64] per wave = Q(16xHD) @ K(64xHD)^T ----
        bf16x8 aq0 = *(const bf16x8*)&Qs[(w * 16 + fr) * LDT + fq * 8];
        bf16x8 aq1 = *(const bf16x8*)&Qs[(w * 16 + fr) * LDT + 32 + fq * 8];
        f32x4 sc[4];
#pragma unroll
        for (int nt = 0; nt < 4; nt++) {
            bf16x8 b0 = *(const bf16x8*)&Ks[(nt * 16 + fr) * LDT + fq * 8];
            bf16x8 b1 = *(const bf16x8*)&Ks[(nt * 16 + fr) * LDT + 32 + fq * 8];
            f32x4 t = (f32x4){0.f, 0.f, 0.f, 0.f};
            t = __builtin_amdgcn_mfma_f32_16x16x32_bf16(aq0, b0, t, 0, 0, 0);
            t = __builtin_amdgcn_mfma_f32_16x16x32_bf16(aq1, b1, t, 0, 0, 0);
            sc[nt] = t;
        }

        // ---- online softmax (row = fq*4+r, cols spread over 16 lanes) ----
        float alpha[4];
#pragma unroll
        for (int r = 0; r < 4; r++) {
            float mt = fmaxf(fmaxf(sc[0][r], sc[1][r]), fmaxf(sc[2][r], sc[3][r]));
#pragma unroll
            for (int msk = 1; msk < 16; msk <<= 1)
                mt = fmaxf(mt, __shfl_xor(mt, msk, 16));
            const float mn = fmaxf(m[r], mt);
            alpha[r] = __expf(m[r] - mn);
            m[r] = mn;
            float ss = 0.f;
#pragma unroll
            for (int nt = 0; nt < 4; nt++) {
                const float p = __expf(sc[nt][r] - mn);
                sc[nt][r] = p;
                ss += p;
            }
#pragma unroll
            for (int msk = 1; msk < 16; msk <<= 1)
                ss += __shfl_xor(ss, msk, 16);
            l[r] = l[r] * alpha[r] + ss;
        }

        // ---- P -> LDS (bf16, A-operand layout source) ----
#pragma unroll
        for (int nt = 0; nt < 4; nt++)
#pragma unroll
            for (int r = 0; r < 4; r++)
                Ps[(w * 16 + fq * 4 + r) * LDT + nt * 16 + fr] = f2bf(sc[nt][r]);
        // (within-wave write->read; compiler inserts lgkmcnt wait)

        // ---- PV: O[16x64] += P(16x64) @ V(64keys x 64dims) ----
        bf16x8 ap0 = *(const bf16x8*)&Ps[(w * 16 + fr) * LDT + fq * 8];
        bf16x8 ap1 = *(const bf16x8*)&Ps[(w * 16 + fr) * LDT + 32 + fq * 8];
#pragma unroll
        for (int nt = 0; nt < 4; nt++) {
            bf16x8 b0 = *(const bf16x8*)&Vs[(nt * 16 + fr) * LDT + fq * 8];
            bf16x8 b1 = *(const bf16x8*)&Vs[(nt * 16 + fr) * LDT + 32 + fq * 8];
            f32x4 t = acc[nt];
            t[0] *= alpha[0]; t[1] *= alpha[1]; t[2] *= alpha[2]; t[3] *= alpha[3];
            t = __builtin_amdgcn_mfma_f32_16x16x32_bf16(ap0, b0, t, 0, 0, 0);
            t = __builtin_amdgcn_mfma_f32_16x16x32_bf16(ap1, b1, t, 0, 0, 0);
            acc[nt] = t;
        }
    }

    // ---- epilogue ----
#pragma unroll
    for (int r = 0; r < 4; r++) {
        const float inv = 1.0f / l[r];
#pragma unroll
        for (int nt = 0; nt < 4; nt++)
            o[(size_t)(q0 + w * 16 + fq * 4 + r) * H_ + h * HD_ + nt * 16 + fr] =
                f2bf(acc[nt][r] * inv);
    }
}

// ---------------------------------------------------------------------------
// RMSNorm, dual fp32 + bf16 output. One block (256 threads) per row.
// ---------------------------------------------------------------------------
__global__ __launch_bounds__(256) void rmsnorm_dual_k(
    const float* __restrict__ x, const float* __restrict__ w,
    float* __restrict__ y, ushort* __restrict__ yb)
{
    const int row = blockIdx.x;
    const float* xr = x + (size_t)row * H_;
    __shared__ float red[256];

    float s = 0.f;
#pragma unroll
    for (int i = 0; i < 8; i++) {
        const float v = xr[threadIdx.x + i * 256];
        s += v * v;
    }
    red[threadIdx.x] = s;
    __syncthreads();
    for (int t = 128; t > 0; t >>= 1) {
        if (threadIdx.x < t) red[threadIdx.x] += red[threadIdx.x + t];
        __syncthreads();
    }
    const float scale = rsqrtf(red[0] * (1.0f / H_) + EPS_);
#pragma unroll
    for (int i = 0; i < 8; i++) {
        const int idx = threadIdx.x + i * 256;
        const float v = xr[idx] * scale * w[idx];
        y[(size_t)row * H_ + idx] = v;
        yb[(size_t)row * H_ + idx] = f2bf(v);
    }
}

// ---------------------------------------------------------------------------
// bf16 silu-mul in place: g = silu(g) * u. n4 = n/4.
// ---------------------------------------------------------------------------
__global__ __launch_bounds__(256) void silu_mul_bf_k(
    ushort* __restrict__ g, const ushort* __restrict__ u, int n4)
{
    int i = blockIdx.x * 256 + threadIdx.x;
    const int stride = gridDim.x * 256;
    for (; i < n4; i += stride) {
        ushort4 gv = ((ushort4*)g)[i];
        ushort4 uv = ((const ushort4*)u)[i];
        float x0 = bf2f(gv.x), x1 = bf2f(gv.y), x2 = bf2f(gv.z), x3 = bf2f(gv.w);
        x0 = x0 / (1.f + __expf(-x0)) * bf2f(uv.x);
        x1 = x1 / (1.f + __expf(-x1)) * bf2f(uv.y);
        x2 = x2 / (1.f + __expf(-x2)) * bf2f(uv.z);
        x3 = x3 / (1.f + __expf(-x3)) * bf2f(uv.w);
        ushort4 r = {f2bf(x0), f2bf(x1), f2bf(x2), f2bf(x3)};
        ((ushort4*)g)[i] = r;
    }
}

// ---------------------------------------------------------------------------
extern "C" void kernel_launch(void* const* d_in, const int* in_sizes, int n_in,
                              void* d_out, int out_size, void* d_ws, size_t ws_size,
                              hipStream_t stream)
{
    (void)in_sizes; (void)n_in; (void)out_size; (void)ws_size;

    const float* hidden      = (const float*)d_in[0];
    const float* comp_w      = (const float*)d_in[1];
    const float* comp_b      = (const float*)d_in[2];
    const float* q_w         = (const float*)d_in[3];
    const float* k_w         = (const float*)d_in[4];
    const float* v_w         = (const float*)d_in[5];
    const float* o_w         = (const float*)d_in[6];
    const float* attn_norm_w = (const float*)d_in[7];
    const float* mlp_norm_w  = (const float*)d_in[8];
    const float* gate_w      = (const float*)d_in[9];
    const float* up_w        = (const float*)d_in[10];
    const float* down_w      = (const float*)d_in[11];
    float* out = (float*)d_out;

    char* p = (char*)d_ws;
    auto alloc = [&](size_t bytes) -> char* {
        char* r = p; p += (bytes + 255) & ~(size_t)255; return r;
    };
    // bf16 weights
    ushort* qw_bf    = (ushort*)alloc((size_t)H_ * H_ * 2);
    ushort* kw_bf    = (ushort*)alloc((size_t)KV_ * H_ * 2);
    ushort* vw_bf    = (ushort*)alloc((size_t)KV_ * H_ * 2);
    ushort* ow_bf    = (ushort*)alloc((size_t)H_ * H_ * 2);
    ushort* gate_bf  = (ushort*)alloc((size_t)FF_ * H_ * 2);
    ushort* up_bf    = (ushort*)alloc((size_t)FF_ * H_ * 2);
    ushort* down_bf  = (ushort*)alloc((size_t)H_ * FF_ * 2);
    ushort* compw_bf = (ushort*)alloc((size_t)COMP_ * S_ * 2);
    ushort* hid_bf   = (ushort*)alloc((size_t)S_ * H_ * 2);
    ushort* hidT     = (ushort*)alloc((size_t)H_ * S_ * 2);
    // fp32 activations (residual chain)
    float* comp0 = (float*)alloc((size_t)COMP_ * H_ * 4);
    float* comp1 = (float*)alloc((size_t)COMP_ * H_ * 4);
    float* ct    = (float*)alloc((size_t)COMP_ * H_ * 4);
    float* ct2   = (float*)alloc((size_t)COMP_ * H_ * 4);
    // bf16 activations
    ushort* ct_bf  = (ushort*)alloc((size_t)COMP_ * H_ * 2);
    ushort* ct2_bf = (ushort*)alloc((size_t)COMP_ * H_ * 2);
    ushort* cur_bf = (ushort*)alloc((size_t)COMP_ * H_ * 2);
    ushort* ob_bf  = (ushort*)alloc((size_t)COMP_ * H_ * 2);
    ushort* qb_bf  = (ushort*)alloc((size_t)COMP_ * H_ * 2);
    ushort* kb_bf  = (ushort*)alloc((size_t)TOT_ * KV_ * 2);
    ushort* vb_bf  = (ushort*)alloc((size_t)TOT_ * KV_ * 2);
    ushort* vt_bf  = (ushort*)alloc((size_t)KV_ * TOT_ * 2);
    ushort* gb_bf  = (ushort*)alloc((size_t)COMP_ * FF_ * 2);
    ushort* ub_bf  = (ushort*)alloc((size_t)COMP_ * FF_ * 2);

    const dim3 blk(256);

    // ---- one-time converts ----
    f2b_k<<<512, blk, 0, stream>>>(q_w,    qw_bf,    H_ * H_ / 4);
    f2b_k<<<512, blk, 0, stream>>>(k_w,    kw_bf,    KV_ * H_ / 4);
    f2b_k<<<512, blk, 0, stream>>>(v_w,    vw_bf,    KV_ * H_ / 4);
    f2b_k<<<512, blk, 0, stream>>>(o_w,    ow_bf,    H_ * H_ / 4);
    f2b_k<<<512, blk, 0, stream>>>(gate_w, gate_bf,  FF_ * H_ / 4);
    f2b_k<<<512, blk, 0, stream>>>(up_w,   up_bf,    FF_ * H_ / 4);
    f2b_k<<<512, blk, 0, stream>>>(down_w, down_bf,  H_ * FF_ / 4);
    f2b_k<<<512, blk, 0, stream>>>(comp_w, compw_bf, COMP_ * S_ / 4);
    f2b_k<<<512, blk, 0, stream>>>(hidden, hid_bf,   S_ * H_ / 4);
    // hidT = hid^T (for the NN-layout compression GEMM)
    tpose64<<<dim3(S_ / 64, H_ / 64), blk, 0, stream>>>(hid_bf, hidT, S_, H_);

    // compressed = comp_w @ hidden + comp_b  (via A@B^T with B = hid^T)
    mfma_gemm<<<dim3(H_ / 128, COMP_ / 128), blk, 0, stream>>>(
        compw_bf, hidT, nullptr, comp_b, 1.f, comp0, cur_bf, COMP_, H_, S_);

    float* cur = comp0;
    for (int d = 0; d < 2; d++) {
        rmsnorm_dual_k<<<COMP_, blk, 0, stream>>>(cur, attn_norm_w, ct, ct_bf);

        // q = 0.125 * (ct @ q_w^T), bf16 only
        mfma_gemm<<<dim3(H_ / 128, COMP_ / 128), blk, 0, stream>>>(
            ct_bf, qw_bf, nullptr, nullptr, 0.125f, nullptr, qb_bf, COMP_, H_, H_);

        // k = [hidden; compressed] @ k_w^T  (bf16)
        mfma_gemm<<<dim3(KV_ / 128, S_ / 128), blk, 0, stream>>>(
            hid_bf, kw_bf, nullptr, nullptr, 1.f, nullptr, kb_bf, S_, KV_, H_);
        mfma_gemm<<<dim3(KV_ / 128, COMP_ / 128), blk, 0, stream>>>(
            cur_bf, kw_bf, nullptr, nullptr, 1.f, nullptr,
            kb_bf + (size_t)S_ * KV_, COMP_, KV_, H_);

        // v likewise, then transpose for attention B-operand
        mfma_gemm<<<dim3(KV_ / 128, S_ / 128), blk, 0, stream>>>(
            hid_bf, vw_bf, nullptr, nullptr, 1.f, nullptr, vb_bf, S_, KV_, H_);
        mfma_gemm<<<dim3(KV_ / 128, COMP_ / 128), blk, 0, stream>>>(
            cur_bf, vw_bf, nullptr, nullptr, 1.f, nullptr,
            vb_bf + (size_t)S_ * KV_, COMP_, KV_, H_);
        tpose64<<<dim3(TOT_ / 64, KV_ / 64), blk, 0, stream>>>(vb_bf, vt_bf, TOT_, KV_);

        // attention (MFMA flash)
        attn_mfma<<<dim3(COMP_ / 64, NH_), blk, 0, stream>>>(qb_bf, kb_bf, vt_bf, ob_bf);

        // compressed = o @ o_w^T + ct
        mfma_gemm<<<dim3(H_ / 128, COMP_ / 128), blk, 0, stream>>>(
            ob_bf, ow_bf, ct, nullptr, 1.f, comp1, nullptr, COMP_, H_, H_);

        rmsnorm_dual_k<<<COMP_, blk, 0, stream>>>(comp1, mlp_norm_w, ct2, ct2_bf);

        // gate / up
        mfma_gemm<<<dim3(FF_ / 128, COMP_ / 128), blk, 0, stream>>>(
            ct2_bf, gate_bf, nullptr, nullptr, 1.f, nullptr, gb_bf, COMP_, FF_, H_);
        mfma_gemm<<<dim3(FF_ / 128, COMP_ / 128), blk, 0, stream>>>(
            ct2_bf, up_bf, nullptr, nullptr, 1.f, nullptr, ub_bf, COMP_, FF_, H_);

        silu_mul_bf_k<<<1024, blk, 0, stream>>>(gb_bf, ub_bf, COMP_ * FF_ / 4);

        // compressed = g @ down_w^T + ct2
        float* dst = (d == 1) ? out : comp0;
        ushort* dst_bf = (d == 1) ? nullptr : cur_bf;
        mfma_gemm<<<dim3(H_ / 128, COMP_ / 128), blk, 0, stream>>>(
            gb_bf, down_bf, ct2, nullptr, 1.f, dst, dst_bf, COMP_, H_, FF_);
        cur = dst;
    }
}

// Round 5
// 995.215 us; speedup vs baseline: 11.5172x; 1.6840x over previous
//
#include <hip/hip_runtime.h>
#include <math.h>

// Problem constants (Compress_30047591202836)
constexpr int S_   = 2048;
constexpr int H_   = 2048;
constexpr int NH_  = 32;
constexpr int NKV_ = 8;
constexpr int HD_  = 64;
constexpr int GROUPS_ = NH_ / NKV_;     // 4
constexpr int KV_  = NKV_ * HD_;        // 512
constexpr int KV2_ = 2 * KV_;           // 1024 (k|v fused)
constexpr int COMP_ = 1024;             // S * 0.5
constexpr int FF_  = 5632;
constexpr int GU2_ = 2 * FF_;           // 11264 (gate|up fused)
constexpr int TOT_ = S_ + COMP_;        // 3072
constexpr float EPS_ = 1e-6f;
constexpr int SK_ = 4;                  // split-K factor

typedef __attribute__((ext_vector_type(4))) float f32x4;
typedef __attribute__((ext_vector_type(8))) short bf16x8;
typedef __attribute__((ext_vector_type(8))) ushort u16x8;

__device__ __forceinline__ ushort f2bf(float x) {
    union { float f; unsigned u; } v; v.f = x;
    unsigned r = v.u + 0x7fffu + ((v.u >> 16) & 1u);   // RNE
    return (ushort)(r >> 16);
}
__device__ __forceinline__ float bf2f(ushort x) {
    union { unsigned u; float f; } v; v.u = ((unsigned)x) << 16;
    return v.f;
}

// ---------------------------------------------------------------------------
// fp32 -> bf16 convert, float4/ushort4 grid-stride. n4 = n/4.
// ---------------------------------------------------------------------------
__global__ __launch_bounds__(256) void f2b_k(
    const float* __restrict__ x, ushort* __restrict__ y, int n4)
{
    int i = blockIdx.x * 256 + threadIdx.x;
    const int stride = gridDim.x * 256;
    for (; i < n4; i += stride) {
        float4 v = ((const float4*)x)[i];
        ushort4 r = {f2bf(v.x), f2bf(v.y), f2bf(v.z), f2bf(v.w)};
        ((ushort4*)y)[i] = r;
    }
}

// ---------------------------------------------------------------------------
// bf16 64x64 tiled transpose: out[(c0+j)*R + r] = in[(r0+r)*ldi + c0+j].
// Grid (R/64, C/64). in row-stride ldi; out compact (C, R).
// ---------------------------------------------------------------------------
__global__ __launch_bounds__(256) void tpose64(
    const ushort* __restrict__ in, ushort* __restrict__ out,
    int R, int C, int ldi)
{
    __shared__ ushort T[64][72];
    const int r0 = blockIdx.x * 64, c0 = blockIdx.y * 64;
    const int row = threadIdx.x >> 2, seg = threadIdx.x & 3;

    const ushort* g = &in[(size_t)(r0 + row) * ldi + c0 + seg * 16];
    *(u16x8*)&T[row][seg * 16]     = *(const u16x8*)g;
    *(u16x8*)&T[row][seg * 16 + 8] = *(const u16x8*)(g + 8);
    __syncthreads();

    ushort tmp[16];
#pragma unroll
    for (int j = 0; j < 16; j++) tmp[j] = T[seg * 16 + j][row];
    ushort* go = &out[(size_t)(c0 + row) * R + r0 + seg * 16];
    *(u16x8*)go       = *(const u16x8*)&tmp[0];
    *(u16x8*)(go + 8) = *(const u16x8*)&tmp[8];
}

// ---------------------------------------------------------------------------
// bf16 MFMA GEMM (non-split): C = oscale*(A@B^T)+bias+addp -> outf/outb.
// 128x128 tile, BK=32, 4 waves, 4x4 mfma_f32_16x16x32_bf16 per wave.
// Used only where the grid is already large (gate|up fused: 704 blocks).
// ---------------------------------------------------------------------------
__global__ __launch_bounds__(256) void mfma_gemm(
    const ushort* __restrict__ A, const ushort* __restrict__ B,
    const float* __restrict__ addp, const float* __restrict__ bias,
    float oscale, float* __restrict__ outf, ushort* __restrict__ outb,
    int M, int N, int K)
{
    __shared__ ushort Alds[128 * 32];
    __shared__ ushort Blds[128 * 32];

    const int tid  = threadIdx.x;
    const int w    = tid >> 6;
    const int lane = tid & 63;
    const int bm = blockIdx.y, bn = blockIdx.x;
    const int wr = w >> 1, wc = w & 1;
    const int fr = lane & 15;
    const int fq = lane >> 4;
    const int srow = lane >> 2;
    const int skof = (lane & 3) * 8;

    f32x4 acc[4][4];
#pragma unroll
    for (int i = 0; i < 4; i++)
#pragma unroll
        for (int j = 0; j < 4; j++)
            acc[i][j] = (f32x4){0.f, 0.f, 0.f, 0.f};

    for (int k0 = 0; k0 < K; k0 += 32) {
        __syncthreads();
#pragma unroll
        for (int i = 0; i < 2; i++) {
            const int slot = w * 2 + i;
            const ushort* ga = &A[(size_t)(bm * 128 + slot * 16 + srow) * K + k0 + skof];
            __builtin_amdgcn_global_load_lds(
                (const __attribute__((address_space(1))) void*)ga,
                (__attribute__((address_space(3))) void*)&Alds[slot * 512], 16, 0, 0);
            const ushort* gb = &B[(size_t)(bn * 128 + slot * 16 + srow) * K + k0 + skof];
            __builtin_amdgcn_global_load_lds(
                (const __attribute__((address_space(1))) void*)gb,
                (__attribute__((address_space(3))) void*)&Blds[slot * 512], 16, 0, 0);
        }
        __syncthreads();

        bf16x8 a[4], b[4];
#pragma unroll
        for (int mt = 0; mt < 4; mt++)
            a[mt] = *(const bf16x8*)&Alds[(wr * 64 + mt * 16 + fr) * 32 + fq * 8];
#pragma unroll
        for (int nt = 0; nt < 4; nt++)
            b[nt] = *(const bf16x8*)&Blds[(wc * 64 + nt * 16 + fr) * 32 + fq * 8];

#pragma unroll
        for (int mt = 0; mt < 4; mt++)
#pragma unroll
            for (int nt = 0; nt < 4; nt++)
                acc[mt][nt] = __builtin_amdgcn_mfma_f32_16x16x32_bf16(
                    a[mt], b[nt], acc[mt][nt], 0, 0, 0);
    }

#pragma unroll
    for (int mt = 0; mt < 4; mt++) {
#pragma unroll
        for (int nt = 0; nt < 4; nt++) {
#pragma unroll
            for (int r = 0; r < 4; r++) {
                const int row = bm * 128 + wr * 64 + mt * 16 + fq * 4 + r;
                const int col = bn * 128 + wc * 64 + nt * 16 + fr;
                float v = acc[mt][nt][r] * oscale;
                if (bias) v += bias[row];
                if (addp) v += addp[(size_t)row * N + col];
                if (outf) outf[(size_t)row * N + col] = v;
                if (outb) outb[(size_t)row * N + col] = f2bf(v);
            }
        }
    }
}

// ---------------------------------------------------------------------------
// Split-K MFMA GEMM: grid.z = SK slices of K (each Kc wide). Raw fp32
// partials to part[z][M][N]; epilogue lives in sk_reduce.
// ---------------------------------------------------------------------------
__global__ __launch_bounds__(256) void mfma_gemm_sk(
    const ushort* __restrict__ A, const ushort* __restrict__ B,
    float* __restrict__ part, int M, int N, int K, int Kc)
{
    __shared__ ushort Alds[128 * 32];
    __shared__ ushort Blds[128 * 32];

    const int tid  = threadIdx.x;
    const int w    = tid >> 6;
    const int lane = tid & 63;
    const int bm = blockIdx.y, bn = blockIdx.x, z = blockIdx.z;
    const int wr = w >> 1, wc = w & 1;
    const int fr = lane & 15;
    const int fq = lane >> 4;
    const int srow = lane >> 2;
    const int skof = (lane & 3) * 8;

    f32x4 acc[4][4];
#pragma unroll
    for (int i = 0; i < 4; i++)
#pragma unroll
        for (int j = 0; j < 4; j++)
            acc[i][j] = (f32x4){0.f, 0.f, 0.f, 0.f};

    const int kbeg = z * Kc;
    for (int k0 = kbeg; k0 < kbeg + Kc; k0 += 32) {
        __syncthreads();
#pragma unroll
        for (int i = 0; i < 2; i++) {
            const int slot = w * 2 + i;
            const ushort* ga = &A[(size_t)(bm * 128 + slot * 16 + srow) * K + k0 + skof];
            __builtin_amdgcn_global_load_lds(
                (const __attribute__((address_space(1))) void*)ga,
                (__attribute__((address_space(3))) void*)&Alds[slot * 512], 16, 0, 0);
            const ushort* gb = &B[(size_t)(bn * 128 + slot * 16 + srow) * K + k0 + skof];
            __builtin_amdgcn_global_load_lds(
                (const __attribute__((address_space(1))) void*)gb,
                (__attribute__((address_space(3))) void*)&Blds[slot * 512], 16, 0, 0);
        }
        __syncthreads();

        bf16x8 a[4], b[4];
#pragma unroll
        for (int mt = 0; mt < 4; mt++)
            a[mt] = *(const bf16x8*)&Alds[(wr * 64 + mt * 16 + fr) * 32 + fq * 8];
#pragma unroll
        for (int nt = 0; nt < 4; nt++)
            b[nt] = *(const bf16x8*)&Blds[(wc * 64 + nt * 16 + fr) * 32 + fq * 8];

#pragma unroll
        for (int mt = 0; mt < 4; mt++)
#pragma unroll
            for (int nt = 0; nt < 4; nt++)
                acc[mt][nt] = __builtin_amdgcn_mfma_f32_16x16x32_bf16(
                    a[mt], b[nt], acc[mt][nt], 0, 0, 0);
    }

    float* pz = part + (size_t)z * M * N;
#pragma unroll
    for (int mt = 0; mt < 4; mt++)
#pragma unroll
        for (int nt = 0; nt < 4; nt++)
#pragma unroll
            for (int r = 0; r < 4; r++) {
                const int row = bm * 128 + wr * 64 + mt * 16 + fq * 4 + r;
                const int col = bn * 128 + wc * 64 + nt * 16 + fr;
                pz[(size_t)row * N + col] = acc[mt][nt][r];
            }
}

// ---------------------------------------------------------------------------
// Split-K reduce + epilogue: v = oscale*sum_z(part) + bias[row] + addp;
// writes fp32 outf and/or bf16 outb. mn4 = M*N/4, n4 = N/4.
// ---------------------------------------------------------------------------
__global__ __launch_bounds__(256) void sk_reduce(
    const float* __restrict__ part, int mn4, int n4,
    const float* __restrict__ bias, const float* __restrict__ addp,
    float oscale, float* __restrict__ outf, ushort* __restrict__ outb)
{
    const size_t mn = (size_t)mn4 * 4;
    int i = blockIdx.x * 256 + threadIdx.x;
    const int stride = gridDim.x * 256;
    for (; i < mn4; i += stride) {
        float4 v = ((const float4*)part)[i];
#pragma unroll
        for (int z = 1; z < SK_; z++) {
            const float4 pz = ((const float4*)(part + z * mn))[i];
            v.x += pz.x; v.y += pz.y; v.z += pz.z; v.w += pz.w;
        }
        v.x *= oscale; v.y *= oscale; v.z *= oscale; v.w *= oscale;
        if (bias) {
            const float bb = bias[i / n4];
            v.x += bb; v.y += bb; v.z += bb; v.w += bb;
        }
        if (addp) {
            const float4 ad = ((const float4*)addp)[i];
            v.x += ad.x; v.y += ad.y; v.z += ad.z; v.w += ad.w;
        }
        if (outf) ((float4*)outf)[i] = v;
        if (outb) {
            ushort4 r = {f2bf(v.x), f2bf(v.y), f2bf(v.z), f2bf(v.w)};
            ((ushort4*)outb)[i] = r;
        }
    }
}

// ---------------------------------------------------------------------------
// MFMA flash attention (bf16 in/out, fp32 softmax state).
//   q : (COMP_, H_) bf16, PRE-SCALED by 1/sqrt(HD)
//   k : rows of fused kv buffer, row-stride ldk (k part)
//   vt: (KV_, TOT_) bf16 transposed V
//   o : (COMP_, H_) bf16
// ---------------------------------------------------------------------------
__global__ __launch_bounds__(256) void attn_mfma(
    const ushort* __restrict__ q, const ushort* __restrict__ k, int ldk,
    const ushort* __restrict__ vt, ushort* __restrict__ o)
{
    constexpr int LDT = 72;
    __shared__ ushort Qs[64 * LDT];
    __shared__ ushort Ks[64 * LDT];
    __shared__ ushort Vs[64 * LDT];
    __shared__ ushort Ps[64 * LDT];

    const int qt = blockIdx.x, h = blockIdx.y;
    const int kvh = h / GROUPS_;
    const int tid = threadIdx.x;
    const int w = tid >> 6, lane = tid & 63;
    const int fr = lane & 15, fq = lane >> 4;
    const int q0 = qt * 64;

    {
        const int row = tid >> 2, seg = tid & 3;
        const ushort* g = &q[(size_t)(q0 + row) * H_ + h * HD_ + seg * 16];
        *(u16x8*)&Qs[row * LDT + seg * 16]     = *(const u16x8*)g;
        *(u16x8*)&Qs[row * LDT + seg * 16 + 8] = *(const u16x8*)(g + 8);
    }

    float m[4] = {-1e30f, -1e30f, -1e30f, -1e30f};
    float l[4] = {0.f, 0.f, 0.f, 0.f};
    f32x4 acc[4];
#pragma unroll
    for (int nt = 0; nt < 4; nt++) acc[nt] = (f32x4){0.f, 0.f, 0.f, 0.f};

    for (int t0 = 0; t0 < TOT_; t0 += 64) {
        __syncthreads();
        {
            const int row = tid >> 2, seg = tid & 3;
            const ushort* gk = &k[(size_t)(t0 + row) * ldk + kvh * HD_ + seg * 16];
            u16x8 k0v = *(const u16x8*)gk;
            u16x8 k1v = *(const u16x8*)(gk + 8);
            const ushort* gv = &vt[(size_t)(kvh * HD_ + row) * TOT_ + t0 + seg * 16];
            u16x8 v0v = *(const u16x8*)gv;
            u16x8 v1v = *(const u16x8*)(gv + 8);
            *(u16x8*)&Ks[row * LDT + seg * 16]     = k0v;
            *(u16x8*)&Ks[row * LDT + seg * 16 + 8] = k1v;
            *(u16x8*)&Vs[row * LDT + seg * 16]     = v0v;
            *(u16x8*)&Vs[row * LDT + seg * 16 + 8] = v1v;
        }
        __syncthreads();

        bf16x8 aq0 = *(const bf16x8*)&Qs[(w * 16 + fr) * LDT + fq * 8];
        bf16x8 aq1 = *(const bf16x8*)&Qs[(w * 16 + fr) * LDT + 32 + fq * 8];
        f32x4 sc[4];
#pragma unroll
        for (int nt = 0; nt < 4; nt++) {
            bf16x8 b0 = *(const bf16x8*)&Ks[(nt * 16 + fr) * LDT + fq * 8];
            bf16x8 b1 = *(const bf16x8*)&Ks[(nt * 16 + fr) * LDT + 32 + fq * 8];
            f32x4 t = (f32x4){0.f, 0.f, 0.f, 0.f};
            t = __builtin_amdgcn_mfma_f32_16x16x32_bf16(aq0, b0, t, 0, 0, 0);
            t = __builtin_amdgcn_mfma_f32_16x16x32_bf16(aq1, b1, t, 0, 0, 0);
            sc[nt] = t;
        }

        float alpha[4];
#pragma unroll
        for (int r = 0; r < 4; r++) {
            float mt = fmaxf(fmaxf(sc[0][r], sc[1][r]), fmaxf(sc[2][r], sc[3][r]));
#pragma unroll
            for (int msk = 1; msk < 16; msk <<= 1)
                mt = fmaxf(mt, __shfl_xor(mt, msk, 16));
            const float mn = fmaxf(m[r], mt);
            alpha[r] = __expf(m[r] - mn);
            m[r] = mn;
            float ss = 0.f;
#pragma unroll
            for (int nt = 0; nt < 4; nt++) {
                const float p = __expf(sc[nt][r] - mn);
                sc[nt][r] = p;
                ss += p;
            }
#pragma unroll
            for (int msk = 1; msk < 16; msk <<= 1)
                ss += __shfl_xor(ss, msk, 16);
            l[r] = l[r] * alpha[r] + ss;
        }

#pragma unroll
        for (int nt = 0; nt < 4; nt++)
#pragma unroll
            for (int r = 0; r < 4; r++)
                Ps[(w * 16 + fq * 4 + r) * LDT + nt * 16 + fr] = f2bf(sc[nt][r]);

        bf16x8 ap0 = *(const bf16x8*)&Ps[(w * 16 + fr) * LDT + fq * 8];
        bf16x8 ap1 = *(const bf16x8*)&Ps[(w * 16 + fr) * LDT + 32 + fq * 8];
#pragma unroll
        for (int nt = 0; nt < 4; nt++) {
            bf16x8 b0 = *(const bf16x8*)&Vs[(nt * 16 + fr) * LDT + fq * 8];
            bf16x8 b1 = *(const bf16x8*)&Vs[(nt * 16 + fr) * LDT + 32 + fq * 8];
            f32x4 t = acc[nt];
            t[0] *= alpha[0]; t[1] *= alpha[1]; t[2] *= alpha[2]; t[3] *= alpha[3];
            t = __builtin_amdgcn_mfma_f32_16x16x32_bf16(ap0, b0, t, 0, 0, 0);
            t = __builtin_amdgcn_mfma_f32_16x16x32_bf16(ap1, b1, t, 0, 0, 0);
            acc[nt] = t;
        }
    }

#pragma unroll
    for (int r = 0; r < 4; r++) {
        const float inv = 1.0f / l[r];
#pragma unroll
        for (int nt = 0; nt < 4; nt++)
            o[(size_t)(q0 + w * 16 + fq * 4 + r) * H_ + h * HD_ + nt * 16 + fr] =
                f2bf(acc[nt][r] * inv);
    }
}

// ---------------------------------------------------------------------------
// RMSNorm, dual fp32 + bf16 output. One block (256 threads) per row.
// ---------------------------------------------------------------------------
__global__ __launch_bounds__(256) void rmsnorm_dual_k(
    const float* __restrict__ x, const float* __restrict__ w,
    float* __restrict__ y, ushort* __restrict__ yb)
{
    const int row = blockIdx.x;
    const float* xr = x + (size_t)row * H_;
    __shared__ float red[256];

    float s = 0.f;
#pragma unroll
    for (int i = 0; i < 8; i++) {
        const float v = xr[threadIdx.x + i * 256];
        s += v * v;
    }
    red[threadIdx.x] = s;
    __syncthreads();
    for (int t = 128; t > 0; t >>= 1) {
        if (threadIdx.x < t) red[threadIdx.x] += red[threadIdx.x + t];
        __syncthreads();
    }
    const float scale = rsqrtf(red[0] * (1.0f / H_) + EPS_);
#pragma unroll
    for (int i = 0; i < 8; i++) {
        const int idx = threadIdx.x + i * 256;
        const float v = xr[idx] * scale * w[idx];
        y[(size_t)row * H_ + idx] = v;
        yb[(size_t)row * H_ + idx] = f2bf(v);
    }
}

// ---------------------------------------------------------------------------
// Fused-gate/up silu-mul: g_out[row][c] = silu(gu[row][c]) * gu[row][FF+c].
// gu row-stride GU2_; output compact (COMP_, FF_). n4 = COMP_*FF_/4.
// ---------------------------------------------------------------------------
__global__ __launch_bounds__(256) void silu_mul_gu(
    const ushort* __restrict__ gu, ushort* __restrict__ g, int n4)
{
    constexpr int FF4 = FF_ / 4;
    int i = blockIdx.x * 256 + threadIdx.x;
    const int stride = gridDim.x * 256;
    for (; i < n4; i += stride) {
        const int row = i / FF4;
        const int c = (i - row * FF4) * 4;
        ushort4 gv = *(const ushort4*)&gu[(size_t)row * GU2_ + c];
        ushort4 uv = *(const ushort4*)&gu[(size_t)row * GU2_ + FF_ + c];
        float x0 = bf2f(gv.x), x1 = bf2f(gv.y), x2 = bf2f(gv.z), x3 = bf2f(gv.w);
        x0 = x0 / (1.f + __expf(-x0)) * bf2f(uv.x);
        x1 = x1 / (1.f + __expf(-x1)) * bf2f(uv.y);
        x2 = x2 / (1.f + __expf(-x2)) * bf2f(uv.z);
        x3 = x3 / (1.f + __expf(-x3)) * bf2f(uv.w);
        ushort4 r = {f2bf(x0), f2bf(x1), f2bf(x2), f2bf(x3)};
        ((ushort4*)g)[i] = r;
    }
}

// ---------------------------------------------------------------------------
extern "C" void kernel_launch(void* const* d_in, const int* in_sizes, int n_in,
                              void* d_out, int out_size, void* d_ws, size_t ws_size,
                              hipStream_t stream)
{
    (void)in_sizes; (void)n_in; (void)out_size; (void)ws_size;

    const float* hidden      = (const float*)d_in[0];
    const float* comp_w      = (const float*)d_in[1];
    const float* comp_b      = (const float*)d_in[2];
    const float* q_w         = (const float*)d_in[3];
    const float* k_w         = (const float*)d_in[4];
    const float* v_w         = (const float*)d_in[5];
    const float* o_w         = (const float*)d_in[6];
    const float* attn_norm_w = (const float*)d_in[7];
    const float* mlp_norm_w  = (const float*)d_in[8];
    const float* gate_w      = (const float*)d_in[9];
    const float* up_w        = (const float*)d_in[10];
    const float* down_w      = (const float*)d_in[11];
    float* out = (float*)d_out;

    char* p = (char*)d_ws;
    auto alloc = [&](size_t bytes) -> char* {
        char* r = p; p += (bytes + 255) & ~(size_t)255; return r;
    };
    // bf16 weights (kv and gate/up fused = stacked rows)
    ushort* qw_bf    = (ushort*)alloc((size_t)H_ * H_ * 2);
    ushort* kvw_bf   = (ushort*)alloc((size_t)KV2_ * H_ * 2);
    ushort* ow_bf    = (ushort*)alloc((size_t)H_ * H_ * 2);
    ushort* guw_bf   = (ushort*)alloc((size_t)GU2_ * H_ * 2);
    ushort* down_bf  = (ushort*)alloc((size_t)H_ * FF_ * 2);
    ushort* compw_bf = (ushort*)alloc((size_t)COMP_ * S_ * 2);
    // bf16 activation buffers
    ushort* hidcomp  = (ushort*)alloc((size_t)TOT_ * H_ * 2);   // [hidden; compressed]
    ushort* hidT     = (ushort*)alloc((size_t)H_ * S_ * 2);
    ushort* ct_bf    = (ushort*)alloc((size_t)COMP_ * H_ * 2);
    ushort* ct2_bf   = (ushort*)alloc((size_t)COMP_ * H_ * 2);
    ushort* ob_bf    = (ushort*)alloc((size_t)COMP_ * H_ * 2);
    ushort* qb_bf    = (ushort*)alloc((size_t)COMP_ * H_ * 2);
    ushort* kvb_bf   = (ushort*)alloc((size_t)TOT_ * KV2_ * 2); // k cols 0..511, v cols 512..1023
    ushort* vt_bf    = (ushort*)alloc((size_t)KV_ * TOT_ * 2);
    ushort* gb_bf    = (ushort*)alloc((size_t)COMP_ * FF_ * 2);
    // fp32 activations (residual chain)
    float* comp0 = (float*)alloc((size_t)COMP_ * H_ * 4);
    float* comp1 = (float*)alloc((size_t)COMP_ * H_ * 4);
    float* ct    = (float*)alloc((size_t)COMP_ * H_ * 4);
    float* ct2   = (float*)alloc((size_t)COMP_ * H_ * 4);
    // split-K scratch (max parts*M*N = 4*3072*1024 floats); aliased w/ gate|up C
    float*  skbuf = (float*)alloc((size_t)SK_ * TOT_ * KV2_ * 4);
    ushort* gub   = (ushort*)skbuf;   // (COMP_, GU2_) bf16 = 23 MB < 50 MB, disjoint in time

    ushort* cur_bf = hidcomp + (size_t)S_ * H_;   // compressed rows of hidcomp

    const dim3 blk(256);

    // ---- one-time converts ----
    f2b_k<<<512, blk, 0, stream>>>(q_w,    qw_bf,            H_ * H_ / 4);
    f2b_k<<<512, blk, 0, stream>>>(k_w,    kvw_bf,           KV_ * H_ / 4);
    f2b_k<<<512, blk, 0, stream>>>(v_w,    kvw_bf + (size_t)KV_ * H_, KV_ * H_ / 4);
    f2b_k<<<512, blk, 0, stream>>>(o_w,    ow_bf,            H_ * H_ / 4);
    f2b_k<<<512, blk, 0, stream>>>(gate_w, guw_bf,           FF_ * H_ / 4);
    f2b_k<<<512, blk, 0, stream>>>(up_w,   guw_bf + (size_t)FF_ * H_, FF_ * H_ / 4);
    f2b_k<<<512, blk, 0, stream>>>(down_w, down_bf,          H_ * FF_ / 4);
    f2b_k<<<512, blk, 0, stream>>>(comp_w, compw_bf,         COMP_ * S_ / 4);
    f2b_k<<<512, blk, 0, stream>>>(hidden, hidcomp,          S_ * H_ / 4);
    tpose64<<<dim3(S_ / 64, H_ / 64), blk, 0, stream>>>(hidcomp, hidT, S_, H_, H_);

    // compressed = comp_w @ hidden + comp_b  (split-K via B = hid^T)
    mfma_gemm_sk<<<dim3(H_ / 128, COMP_ / 128, SK_), blk, 0, stream>>>(
        compw_bf, hidT, skbuf, COMP_, H_, S_, S_ / SK_);
    sk_reduce<<<1024, blk, 0, stream>>>(
        skbuf, COMP_ * H_ / 4, H_ / 4, comp_b, nullptr, 1.f, comp0, cur_bf);

    float* cur = comp0;
    for (int d = 0; d < 2; d++) {
        rmsnorm_dual_k<<<COMP_, blk, 0, stream>>>(cur, attn_norm_w, ct, ct_bf);

        // q = 0.125 * (ct @ q_w^T)   [split-K]
        mfma_gemm_sk<<<dim3(H_ / 128, COMP_ / 128, SK_), blk, 0, stream>>>(
            ct_bf, qw_bf, skbuf, COMP_, H_, H_, H_ / SK_);
        sk_reduce<<<1024, blk, 0, stream>>>(
            skbuf, COMP_ * H_ / 4, H_ / 4, nullptr, nullptr, 0.125f, nullptr, qb_bf);

        // k|v = [hidden; compressed] @ [k_w; v_w]^T   [split-K, fused]
        mfma_gemm_sk<<<dim3(KV2_ / 128, TOT_ / 128, SK_), blk, 0, stream>>>(
            hidcomp, kvw_bf, skbuf, TOT_, KV2_, H_, H_ / SK_);
        sk_reduce<<<1024, blk, 0, stream>>>(
            skbuf, TOT_ * KV2_ / 4, KV2_ / 4, nullptr, nullptr, 1.f, nullptr, kvb_bf);

        // vt = transpose of v half (row-stride KV2_)
        tpose64<<<dim3(TOT_ / 64, KV_ / 64), blk, 0, stream>>>(
            kvb_bf + KV_, vt_bf, TOT_, KV_, KV2_);

        // attention (MFMA flash)
        attn_mfma<<<dim3(COMP_ / 64, NH_), blk, 0, stream>>>(
            qb_bf, kvb_bf, KV2_, vt_bf, ob_bf);

        // compressed = o @ o_w^T + ct   [split-K]
        mfma_gemm_sk<<<dim3(H_ / 128, COMP_ / 128, SK_), blk, 0, stream>>>(
            ob_bf, ow_bf, skbuf, COMP_, H_, H_, H_ / SK_);
        sk_reduce<<<1024, blk, 0, stream>>>(
            skbuf, COMP_ * H_ / 4, H_ / 4, nullptr, ct, 1.f, comp1, nullptr);

        rmsnorm_dual_k<<<COMP_, blk, 0, stream>>>(comp1, mlp_norm_w, ct2, ct2_bf);

        // gate|up fused (grid 88x8 = 704 blocks — no split needed)
        mfma_gemm<<<dim3(GU2_ / 128, COMP_ / 128), blk, 0, stream>>>(
            ct2_bf, guw_bf, nullptr, nullptr, 1.f, nullptr, gub, COMP_, GU2_, H_);

        silu_mul_gu<<<1024, blk, 0, stream>>>(gub, gb_bf, COMP_ * FF_ / 4);

        // compressed = g @ down_w^T + ct2   [split-K, Kc = 1408]
        float* dst = (d == 1) ? out : comp0;
        ushort* dst_bf = (d == 1) ? nullptr : cur_bf;
        mfma_gemm_sk<<<dim3(H_ / 128, COMP_ / 128, SK_), blk, 0, stream>>>(
            gb_bf, down_bf, skbuf, COMP_, H_, FF_, FF_ / SK_);
        sk_reduce<<<1024, blk, 0, stream>>>(
            skbuf, COMP_ * H_ / 4, H_ / 4, nullptr, ct2, 1.f, dst, dst_bf);
        cur = dst;
    }
}

// Round 6
// 967.710 us; speedup vs baseline: 11.8445x; 1.0284x over previous
//
#include <hip/hip_runtime.h>
#include <math.h>

// Problem constants (Compress_30047591202836)
constexpr int S_   = 2048;
constexpr int H_   = 2048;
constexpr int NH_  = 32;
constexpr int NKV_ = 8;
constexpr int HD_  = 64;
constexpr int GROUPS_ = NH_ / NKV_;     // 4
constexpr int KV_  = NKV_ * HD_;        // 512
constexpr int KV2_ = 2 * KV_;           // 1024 (k|v fused)
constexpr int COMP_ = 1024;             // S * 0.5
constexpr int FF_  = 5632;
constexpr int GU2_ = 2 * FF_;           // 11264 (gate|up fused)
constexpr int TOT_ = S_ + COMP_;        // 3072
constexpr float EPS_ = 1e-6f;
constexpr int SK_ = 4;                  // split-K factor (GEMMs)
constexpr int SP_ = 2;                  // KV-split factor (attention)
constexpr float LOG2E_ = 1.44269504088896340736f;

typedef __attribute__((ext_vector_type(4))) float f32x4;
typedef __attribute__((ext_vector_type(8))) short bf16x8;
typedef __attribute__((ext_vector_type(8))) ushort u16x8;

__device__ __forceinline__ ushort f2bf(float x) {
    union { float f; unsigned u; } v; v.f = x;
    unsigned r = v.u + 0x7fffu + ((v.u >> 16) & 1u);   // RNE
    return (ushort)(r >> 16);
}
__device__ __forceinline__ float bf2f(ushort x) {
    union { unsigned u; float f; } v; v.u = ((unsigned)x) << 16;
    return v.f;
}

// ---------------------------------------------------------------------------
// fp32 -> bf16 convert, float4/ushort4 grid-stride. n4 = n/4.
// ---------------------------------------------------------------------------
__global__ __launch_bounds__(256) void f2b_k(
    const float* __restrict__ x, ushort* __restrict__ y, int n4)
{
    int i = blockIdx.x * 256 + threadIdx.x;
    const int stride = gridDim.x * 256;
    for (; i < n4; i += stride) {
        float4 v = ((const float4*)x)[i];
        ushort4 r = {f2bf(v.x), f2bf(v.y), f2bf(v.z), f2bf(v.w)};
        ((ushort4*)y)[i] = r;
    }
}

// ---------------------------------------------------------------------------
// bf16 64x64 tiled transpose: out[(c0+j)*R + r] = in[(r0+r)*ldi + c0+j].
// ---------------------------------------------------------------------------
__global__ __launch_bounds__(256) void tpose64(
    const ushort* __restrict__ in, ushort* __restrict__ out,
    int R, int C, int ldi)
{
    __shared__ ushort T[64][72];
    const int r0 = blockIdx.x * 64, c0 = blockIdx.y * 64;
    const int row = threadIdx.x >> 2, seg = threadIdx.x & 3;

    const ushort* g = &in[(size_t)(r0 + row) * ldi + c0 + seg * 16];
    *(u16x8*)&T[row][seg * 16]     = *(const u16x8*)g;
    *(u16x8*)&T[row][seg * 16 + 8] = *(const u16x8*)(g + 8);
    __syncthreads();

    ushort tmp[16];
#pragma unroll
    for (int j = 0; j < 16; j++) tmp[j] = T[seg * 16 + j][row];
    ushort* go = &out[(size_t)(c0 + row) * R + r0 + seg * 16];
    *(u16x8*)go       = *(const u16x8*)&tmp[0];
    *(u16x8*)(go + 8) = *(const u16x8*)&tmp[8];
}

// ---------------------------------------------------------------------------
// bf16 MFMA GEMM (non-split): C = oscale*(A@B^T)+bias+addp -> outf/outb.
// 128x128 tile, BK=32, 4 waves, 4x4 mfma_f32_16x16x32_bf16 per wave.
// ---------------------------------------------------------------------------
__global__ __launch_bounds__(256) void mfma_gemm(
    const ushort* __restrict__ A, const ushort* __restrict__ B,
    const float* __restrict__ addp, const float* __restrict__ bias,
    float oscale, float* __restrict__ outf, ushort* __restrict__ outb,
    int M, int N, int K)
{
    __shared__ ushort Alds[128 * 32];
    __shared__ ushort Blds[128 * 32];

    const int tid  = threadIdx.x;
    const int w    = tid >> 6;
    const int lane = tid & 63;
    const int bm = blockIdx.y, bn = blockIdx.x;
    const int wr = w >> 1, wc = w & 1;
    const int fr = lane & 15;
    const int fq = lane >> 4;
    const int srow = lane >> 2;
    const int skof = (lane & 3) * 8;

    f32x4 acc[4][4];
#pragma unroll
    for (int i = 0; i < 4; i++)
#pragma unroll
        for (int j = 0; j < 4; j++)
            acc[i][j] = (f32x4){0.f, 0.f, 0.f, 0.f};

    for (int k0 = 0; k0 < K; k0 += 32) {
        __syncthreads();
#pragma unroll
        for (int i = 0; i < 2; i++) {
            const int slot = w * 2 + i;
            const ushort* ga = &A[(size_t)(bm * 128 + slot * 16 + srow) * K + k0 + skof];
            __builtin_amdgcn_global_load_lds(
                (const __attribute__((address_space(1))) void*)ga,
                (__attribute__((address_space(3))) void*)&Alds[slot * 512], 16, 0, 0);
            const ushort* gb = &B[(size_t)(bn * 128 + slot * 16 + srow) * K + k0 + skof];
            __builtin_amdgcn_global_load_lds(
                (const __attribute__((address_space(1))) void*)gb,
                (__attribute__((address_space(3))) void*)&Blds[slot * 512], 16, 0, 0);
        }
        __syncthreads();

        bf16x8 a[4], b[4];
#pragma unroll
        for (int mt = 0; mt < 4; mt++)
            a[mt] = *(const bf16x8*)&Alds[(wr * 64 + mt * 16 + fr) * 32 + fq * 8];
#pragma unroll
        for (int nt = 0; nt < 4; nt++)
            b[nt] = *(const bf16x8*)&Blds[(wc * 64 + nt * 16 + fr) * 32 + fq * 8];

#pragma unroll
        for (int mt = 0; mt < 4; mt++)
#pragma unroll
            for (int nt = 0; nt < 4; nt++)
                acc[mt][nt] = __builtin_amdgcn_mfma_f32_16x16x32_bf16(
                    a[mt], b[nt], acc[mt][nt], 0, 0, 0);
    }

#pragma unroll
    for (int mt = 0; mt < 4; mt++) {
#pragma unroll
        for (int nt = 0; nt < 4; nt++) {
#pragma unroll
            for (int r = 0; r < 4; r++) {
                const int row = bm * 128 + wr * 64 + mt * 16 + fq * 4 + r;
                const int col = bn * 128 + wc * 64 + nt * 16 + fr;
                float v = acc[mt][nt][r] * oscale;
                if (bias) v += bias[row];
                if (addp) v += addp[(size_t)row * N + col];
                if (outf) outf[(size_t)row * N + col] = v;
                if (outb) outb[(size_t)row * N + col] = f2bf(v);
            }
        }
    }
}

// ---------------------------------------------------------------------------
// Split-K MFMA GEMM: grid.z = SK slices of K. Raw fp32 partials to part.
// ---------------------------------------------------------------------------
__global__ __launch_bounds__(256) void mfma_gemm_sk(
    const ushort* __restrict__ A, const ushort* __restrict__ B,
    float* __restrict__ part, int M, int N, int K, int Kc)
{
    __shared__ ushort Alds[128 * 32];
    __shared__ ushort Blds[128 * 32];

    const int tid  = threadIdx.x;
    const int w    = tid >> 6;
    const int lane = tid & 63;
    const int bm = blockIdx.y, bn = blockIdx.x, z = blockIdx.z;
    const int wr = w >> 1, wc = w & 1;
    const int fr = lane & 15;
    const int fq = lane >> 4;
    const int srow = lane >> 2;
    const int skof = (lane & 3) * 8;

    f32x4 acc[4][4];
#pragma unroll
    for (int i = 0; i < 4; i++)
#pragma unroll
        for (int j = 0; j < 4; j++)
            acc[i][j] = (f32x4){0.f, 0.f, 0.f, 0.f};

    const int kbeg = z * Kc;
    for (int k0 = kbeg; k0 < kbeg + Kc; k0 += 32) {
        __syncthreads();
#pragma unroll
        for (int i = 0; i < 2; i++) {
            const int slot = w * 2 + i;
            const ushort* ga = &A[(size_t)(bm * 128 + slot * 16 + srow) * K + k0 + skof];
            __builtin_amdgcn_global_load_lds(
                (const __attribute__((address_space(1))) void*)ga,
                (__attribute__((address_space(3))) void*)&Alds[slot * 512], 16, 0, 0);
            const ushort* gb = &B[(size_t)(bn * 128 + slot * 16 + srow) * K + k0 + skof];
            __builtin_amdgcn_global_load_lds(
                (const __attribute__((address_space(1))) void*)gb,
                (__attribute__((address_space(3))) void*)&Blds[slot * 512], 16, 0, 0);
        }
        __syncthreads();

        bf16x8 a[4], b[4];
#pragma unroll
        for (int mt = 0; mt < 4; mt++)
            a[mt] = *(const bf16x8*)&Alds[(wr * 64 + mt * 16 + fr) * 32 + fq * 8];
#pragma unroll
        for (int nt = 0; nt < 4; nt++)
            b[nt] = *(const bf16x8*)&Blds[(wc * 64 + nt * 16 + fr) * 32 + fq * 8];

#pragma unroll
        for (int mt = 0; mt < 4; mt++)
#pragma unroll
            for (int nt = 0; nt < 4; nt++)
                acc[mt][nt] = __builtin_amdgcn_mfma_f32_16x16x32_bf16(
                    a[mt], b[nt], acc[mt][nt], 0, 0, 0);
    }

    float* pz = part + (size_t)z * M * N;
#pragma unroll
    for (int mt = 0; mt < 4; mt++)
#pragma unroll
        for (int nt = 0; nt < 4; nt++)
#pragma unroll
            for (int r = 0; r < 4; r++) {
                const int row = bm * 128 + wr * 64 + mt * 16 + fq * 4 + r;
                const int col = bn * 128 + wc * 64 + nt * 16 + fr;
                pz[(size_t)row * N + col] = acc[mt][nt][r];
            }
}

// ---------------------------------------------------------------------------
// Split-K reduce + epilogue.
// ---------------------------------------------------------------------------
__global__ __launch_bounds__(256) void sk_reduce(
    const float* __restrict__ part, int mn4, int n4,
    const float* __restrict__ bias, const float* __restrict__ addp,
    float oscale, float* __restrict__ outf, ushort* __restrict__ outb)
{
    const size_t mn = (size_t)mn4 * 4;
    int i = blockIdx.x * 256 + threadIdx.x;
    const int stride = gridDim.x * 256;
    for (; i < mn4; i += stride) {
        float4 v = ((const float4*)part)[i];
#pragma unroll
        for (int z = 1; z < SK_; z++) {
            const float4 pz = ((const float4*)(part + z * mn))[i];
            v.x += pz.x; v.y += pz.y; v.z += pz.z; v.w += pz.w;
        }
        v.x *= oscale; v.y *= oscale; v.z *= oscale; v.w *= oscale;
        if (bias) {
            const float bb = bias[i / n4];
            v.x += bb; v.y += bb; v.z += bb; v.w += bb;
        }
        if (addp) {
            const float4 ad = ((const float4*)addp)[i];
            v.x += ad.x; v.y += ad.y; v.z += ad.z; v.w += ad.w;
        }
        if (outf) ((float4*)outf)[i] = v;
        if (outb) {
            ushort4 r = {f2bf(v.x), f2bf(v.y), f2bf(v.z), f2bf(v.w)};
            ((ushort4*)outb)[i] = r;
        }
    }
}

// ---------------------------------------------------------------------------
// MFMA flash attention, KV-split (grid.z = SP_ splits of the key range).
//   q : (COMP_, H_) bf16, PRE-SCALED by log2(e)/sqrt(HD)  (exp2 domain)
//   k : fused kv buffer rows, row-stride ldk (k half)
//   vt: (KV_, TOT_) bf16 transposed V
// Emits unnormalized fp32 O-partials (attp[z]) + per-row (m,l) pairs (ml).
// Softmax state in the exp2 domain throughout. 36 KB LDS -> 4 blocks/CU;
// grid 16x32x2 = 1024 blocks = 4/CU.
// ---------------------------------------------------------------------------
__global__ __launch_bounds__(256) void attn_mfma(
    const ushort* __restrict__ q, const ushort* __restrict__ k, int ldk,
    const ushort* __restrict__ vt, float* __restrict__ attp,
    float* __restrict__ ml)
{
    constexpr int LDT = 72;
    constexpr int KSPAN = TOT_ / SP_;   // 1536 keys per split
    __shared__ ushort Qs[64 * LDT];
    __shared__ ushort Ks[64 * LDT];
    __shared__ ushort Vs[64 * LDT];
    __shared__ ushort Ps[64 * LDT];

    const int qt = blockIdx.x, h = blockIdx.y, z = blockIdx.z;
    const int kvh = h / GROUPS_;
    const int tid = threadIdx.x;
    const int w = tid >> 6, lane = tid & 63;
    const int fr = lane & 15, fq = lane >> 4;
    const int q0 = qt * 64;

    {
        const int row = tid >> 2, seg = tid & 3;
        const ushort* g = &q[(size_t)(q0 + row) * H_ + h * HD_ + seg * 16];
        *(u16x8*)&Qs[row * LDT + seg * 16]     = *(const u16x8*)g;
        *(u16x8*)&Qs[row * LDT + seg * 16 + 8] = *(const u16x8*)(g + 8);
    }
    __syncthreads();
    // Q fragments are loop-invariant — hoist them.
    const bf16x8 aq0 = *(const bf16x8*)&Qs[(w * 16 + fr) * LDT + fq * 8];
    const bf16x8 aq1 = *(const bf16x8*)&Qs[(w * 16 + fr) * LDT + 32 + fq * 8];

    float m[4] = {-1e30f, -1e30f, -1e30f, -1e30f};
    float l[4] = {0.f, 0.f, 0.f, 0.f};
    f32x4 acc[4];
#pragma unroll
    for (int nt = 0; nt < 4; nt++) acc[nt] = (f32x4){0.f, 0.f, 0.f, 0.f};

    const int t_beg = z * KSPAN;
    for (int t0 = t_beg; t0 < t_beg + KSPAN; t0 += 64) {
        __syncthreads();
        {
            const int row = tid >> 2, seg = tid & 3;
            const ushort* gk = &k[(size_t)(t0 + row) * ldk + kvh * HD_ + seg * 16];
            u16x8 k0v = *(const u16x8*)gk;
            u16x8 k1v = *(const u16x8*)(gk + 8);
            const ushort* gv = &vt[(size_t)(kvh * HD_ + row) * TOT_ + t0 + seg * 16];
            u16x8 v0v = *(const u16x8*)gv;
            u16x8 v1v = *(const u16x8*)(gv + 8);
            *(u16x8*)&Ks[row * LDT + seg * 16]     = k0v;
            *(u16x8*)&Ks[row * LDT + seg * 16 + 8] = k1v;
            *(u16x8*)&Vs[row * LDT + seg * 16]     = v0v;
            *(u16x8*)&Vs[row * LDT + seg * 16 + 8] = v1v;
        }
        __syncthreads();

        f32x4 sc[4];
#pragma unroll
        for (int nt = 0; nt < 4; nt++) {
            bf16x8 b0 = *(const bf16x8*)&Ks[(nt * 16 + fr) * LDT + fq * 8];
            bf16x8 b1 = *(const bf16x8*)&Ks[(nt * 16 + fr) * LDT + 32 + fq * 8];
            f32x4 t = (f32x4){0.f, 0.f, 0.f, 0.f};
            t = __builtin_amdgcn_mfma_f32_16x16x32_bf16(aq0, b0, t, 0, 0, 0);
            t = __builtin_amdgcn_mfma_f32_16x16x32_bf16(aq1, b1, t, 0, 0, 0);
            sc[nt] = t;
        }

        float alpha[4];
#pragma unroll
        for (int r = 0; r < 4; r++) {
            float mt = fmaxf(fmaxf(sc[0][r], sc[1][r]), fmaxf(sc[2][r], sc[3][r]));
#pragma unroll
            for (int msk = 1; msk < 16; msk <<= 1)
                mt = fmaxf(mt, __shfl_xor(mt, msk, 16));
            const float mn = fmaxf(m[r], mt);
            alpha[r] = exp2f(m[r] - mn);
            m[r] = mn;
            float ss = 0.f;
#pragma unroll
            for (int nt = 0; nt < 4; nt++) {
                const float p = exp2f(sc[nt][r] - mn);
                sc[nt][r] = p;
                ss += p;
            }
#pragma unroll
            for (int msk = 1; msk < 16; msk <<= 1)
                ss += __shfl_xor(ss, msk, 16);
            l[r] = l[r] * alpha[r] + ss;
        }

#pragma unroll
        for (int nt = 0; nt < 4; nt++)
#pragma unroll
            for (int r = 0; r < 4; r++)
                Ps[(w * 16 + fq * 4 + r) * LDT + nt * 16 + fr] = f2bf(sc[nt][r]);

        bf16x8 ap0 = *(const bf16x8*)&Ps[(w * 16 + fr) * LDT + fq * 8];
        bf16x8 ap1 = *(const bf16x8*)&Ps[(w * 16 + fr) * LDT + 32 + fq * 8];
#pragma unroll
        for (int nt = 0; nt < 4; nt++) {
            bf16x8 b0 = *(const bf16x8*)&Vs[(nt * 16 + fr) * LDT + fq * 8];
            bf16x8 b1 = *(const bf16x8*)&Vs[(nt * 16 + fr) * LDT + 32 + fq * 8];
            f32x4 t = acc[nt];
            t[0] *= alpha[0]; t[1] *= alpha[1]; t[2] *= alpha[2]; t[3] *= alpha[3];
            t = __builtin_amdgcn_mfma_f32_16x16x32_bf16(ap0, b0, t, 0, 0, 0);
            t = __builtin_amdgcn_mfma_f32_16x16x32_bf16(ap1, b1, t, 0, 0, 0);
            acc[nt] = t;
        }
    }

    // Unnormalized partial + (m,l) state out.
    float* pz = attp + (size_t)z * COMP_ * H_;
#pragma unroll
    for (int r = 0; r < 4; r++) {
        const int row = q0 + w * 16 + fq * 4 + r;
#pragma unroll
        for (int nt = 0; nt < 4; nt++)
            pz[(size_t)row * H_ + h * HD_ + nt * 16 + fr] = acc[nt][r];
        if (fr == 0)
            ((float2*)ml)[((size_t)z * NH_ + h) * COMP_ + row] =
                make_float2(m[r], l[r]);
    }
}

// ---------------------------------------------------------------------------
// Merge the SP_ KV-splits: o = (sum_z a_z * attp_z) / (sum_z a_z * l_z),
// a_z = 2^(m_z - M). n4 = COMP_*H_/4.
// ---------------------------------------------------------------------------
__global__ __launch_bounds__(256) void attn_merge(
    const float* __restrict__ attp, const float* __restrict__ ml,
    ushort* __restrict__ o, int n4)
{
    constexpr int H4 = H_ / 4;
    constexpr size_t PS = (size_t)COMP_ * H_;
    int i = blockIdx.x * 256 + threadIdx.x;
    const int stride = gridDim.x * 256;
    for (; i < n4; i += stride) {
        const int row = i / H4;
        const int col = (i - row * H4) * 4;
        const int h = col >> 6;          // HD_ = 64
        const float2 ml0 = ((const float2*)ml)[((size_t)0 * NH_ + h) * COMP_ + row];
        const float2 ml1 = ((const float2*)ml)[((size_t)1 * NH_ + h) * COMP_ + row];
        const float M = fmaxf(ml0.x, ml1.x);
        const float a0 = exp2f(ml0.x - M), a1 = exp2f(ml1.x - M);
        const float inv = 1.0f / (a0 * ml0.y + a1 * ml1.y);
        const float4 p0 = ((const float4*)attp)[i];
        const float4 p1 = ((const float4*)(attp + PS))[i];
        ushort4 r = {f2bf((a0 * p0.x + a1 * p1.x) * inv),
                     f2bf((a0 * p0.y + a1 * p1.y) * inv),
                     f2bf((a0 * p0.z + a1 * p1.z) * inv),
                     f2bf((a0 * p0.w + a1 * p1.w) * inv)};
        ((ushort4*)o)[i] = r;
    }
}

// ---------------------------------------------------------------------------
// RMSNorm, dual fp32 + bf16 output. One block (256 threads) per row.
// ---------------------------------------------------------------------------
__global__ __launch_bounds__(256) void rmsnorm_dual_k(
    const float* __restrict__ x, const float* __restrict__ w,
    float* __restrict__ y, ushort* __restrict__ yb)
{
    const int row = blockIdx.x;
    const float* xr = x + (size_t)row * H_;
    __shared__ float red[256];

    float s = 0.f;
#pragma unroll
    for (int i = 0; i < 8; i++) {
        const float v = xr[threadIdx.x + i * 256];
        s += v * v;
    }
    red[threadIdx.x] = s;
    __syncthreads();
    for (int t = 128; t > 0; t >>= 1) {
        if (threadIdx.x < t) red[threadIdx.x] += red[threadIdx.x + t];
        __syncthreads();
    }
    const float scale = rsqrtf(red[0] * (1.0f / H_) + EPS_);
#pragma unroll
    for (int i = 0; i < 8; i++) {
        const int idx = threadIdx.x + i * 256;
        const float v = xr[idx] * scale * w[idx];
        y[(size_t)row * H_ + idx] = v;
        yb[(size_t)row * H_ + idx] = f2bf(v);
    }
}

// ---------------------------------------------------------------------------
// Fused-gate/up silu-mul: g_out[row][c] = silu(gu[row][c]) * gu[row][FF+c].
// ---------------------------------------------------------------------------
__global__ __launch_bounds__(256) void silu_mul_gu(
    const ushort* __restrict__ gu, ushort* __restrict__ g, int n4)
{
    constexpr int FF4 = FF_ / 4;
    int i = blockIdx.x * 256 + threadIdx.x;
    const int stride = gridDim.x * 256;
    for (; i < n4; i += stride) {
        const int row = i / FF4;
        const int c = (i - row * FF4) * 4;
        ushort4 gv = *(const ushort4*)&gu[(size_t)row * GU2_ + c];
        ushort4 uv = *(const ushort4*)&gu[(size_t)row * GU2_ + FF_ + c];
        float x0 = bf2f(gv.x), x1 = bf2f(gv.y), x2 = bf2f(gv.z), x3 = bf2f(gv.w);
        x0 = x0 / (1.f + __expf(-x0)) * bf2f(uv.x);
        x1 = x1 / (1.f + __expf(-x1)) * bf2f(uv.y);
        x2 = x2 / (1.f + __expf(-x2)) * bf2f(uv.z);
        x3 = x3 / (1.f + __expf(-x3)) * bf2f(uv.w);
        ushort4 r = {f2bf(x0), f2bf(x1), f2bf(x2), f2bf(x3)};
        ((ushort4*)g)[i] = r;
    }
}

// ---------------------------------------------------------------------------
extern "C" void kernel_launch(void* const* d_in, const int* in_sizes, int n_in,
                              void* d_out, int out_size, void* d_ws, size_t ws_size,
                              hipStream_t stream)
{
    (void)in_sizes; (void)n_in; (void)out_size; (void)ws_size;

    const float* hidden      = (const float*)d_in[0];
    const float* comp_w      = (const float*)d_in[1];
    const float* comp_b      = (const float*)d_in[2];
    const float* q_w         = (const float*)d_in[3];
    const float* k_w         = (const float*)d_in[4];
    const float* v_w         = (const float*)d_in[5];
    const float* o_w         = (const float*)d_in[6];
    const float* attn_norm_w = (const float*)d_in[7];
    const float* mlp_norm_w  = (const float*)d_in[8];
    const float* gate_w      = (const float*)d_in[9];
    const float* up_w        = (const float*)d_in[10];
    const float* down_w      = (const float*)d_in[11];
    float* out = (float*)d_out;

    char* p = (char*)d_ws;
    auto alloc = [&](size_t bytes) -> char* {
        char* r = p; p += (bytes + 255) & ~(size_t)255; return r;
    };
    // bf16 weights (kv and gate/up fused = stacked rows)
    ushort* qw_bf    = (ushort*)alloc((size_t)H_ * H_ * 2);
    ushort* kvw_bf   = (ushort*)alloc((size_t)KV2_ * H_ * 2);
    ushort* ow_bf    = (ushort*)alloc((size_t)H_ * H_ * 2);
    ushort* guw_bf   = (ushort*)alloc((size_t)GU2_ * H_ * 2);
    ushort* down_bf  = (ushort*)alloc((size_t)H_ * FF_ * 2);
    ushort* compw_bf = (ushort*)alloc((size_t)COMP_ * S_ * 2);
    // bf16 activation buffers
    ushort* hidcomp  = (ushort*)alloc((size_t)TOT_ * H_ * 2);   // [hidden; compressed]
    ushort* hidT     = (ushort*)alloc((size_t)H_ * S_ * 2);
    ushort* ct_bf    = (ushort*)alloc((size_t)COMP_ * H_ * 2);
    ushort* ct2_bf   = (ushort*)alloc((size_t)COMP_ * H_ * 2);
    ushort* ob_bf    = (ushort*)alloc((size_t)COMP_ * H_ * 2);
    ushort* qb_bf    = (ushort*)alloc((size_t)COMP_ * H_ * 2);
    ushort* kvb_bf   = (ushort*)alloc((size_t)TOT_ * KV2_ * 2); // k cols 0..511, v cols 512..1023
    ushort* vt_bf    = (ushort*)alloc((size_t)KV_ * TOT_ * 2);
    ushort* gb_bf    = (ushort*)alloc((size_t)COMP_ * FF_ * 2);
    // fp32 activations (residual chain)
    float* comp0 = (float*)alloc((size_t)COMP_ * H_ * 4);
    float* comp1 = (float*)alloc((size_t)COMP_ * H_ * 4);
    float* ct    = (float*)alloc((size_t)COMP_ * H_ * 4);
    float* ct2   = (float*)alloc((size_t)COMP_ * H_ * 4);
    // split-K scratch; time-shared with gate|up C and attention partials
    float*  skbuf = (float*)alloc((size_t)SK_ * TOT_ * KV2_ * 4);
    ushort* gub   = (ushort*)skbuf;                       // (COMP_, GU2_) bf16
    float*  attp  = skbuf;                                // SP_ x (COMP_, H_) fp32 = 16 MB
    float*  mlbuf = skbuf + (size_t)SP_ * COMP_ * H_;     // SP_*NH_*COMP_ float2

    ushort* cur_bf = hidcomp + (size_t)S_ * H_;   // compressed rows of hidcomp

    const dim3 blk(256);

    // ---- one-time converts ----
    f2b_k<<<512, blk, 0, stream>>>(q_w,    qw_bf,            H_ * H_ / 4);
    f2b_k<<<512, blk, 0, stream>>>(k_w,    kvw_bf,           KV_ * H_ / 4);
    f2b_k<<<512, blk, 0, stream>>>(v_w,    kvw_bf + (size_t)KV_ * H_, KV_ * H_ / 4);
    f2b_k<<<512, blk, 0, stream>>>(o_w,    ow_bf,            H_ * H_ / 4);
    f2b_k<<<512, blk, 0, stream>>>(gate_w, guw_bf,           FF_ * H_ / 4);
    f2b_k<<<512, blk, 0, stream>>>(up_w,   guw_bf + (size_t)FF_ * H_, FF_ * H_ / 4);
    f2b_k<<<512, blk, 0, stream>>>(down_w, down_bf,          H_ * FF_ / 4);
    f2b_k<<<512, blk, 0, stream>>>(comp_w, compw_bf,         COMP_ * S_ / 4);
    f2b_k<<<512, blk, 0, stream>>>(hidden, hidcomp,          S_ * H_ / 4);
    tpose64<<<dim3(S_ / 64, H_ / 64), blk, 0, stream>>>(hidcomp, hidT, S_, H_, H_);

    // compressed = comp_w @ hidden + comp_b  (split-K via B = hid^T)
    mfma_gemm_sk<<<dim3(H_ / 128, COMP_ / 128, SK_), blk, 0, stream>>>(
        compw_bf, hidT, skbuf, COMP_, H_, S_, S_ / SK_);
    sk_reduce<<<1024, blk, 0, stream>>>(
        skbuf, COMP_ * H_ / 4, H_ / 4, comp_b, nullptr, 1.f, comp0, cur_bf);

    float* cur = comp0;
    for (int d = 0; d < 2; d++) {
        rmsnorm_dual_k<<<COMP_, blk, 0, stream>>>(cur, attn_norm_w, ct, ct_bf);

        // q = (log2e/8) * (ct @ q_w^T)   [split-K; exp2-domain scaling]
        mfma_gemm_sk<<<dim3(H_ / 128, COMP_ / 128, SK_), blk, 0, stream>>>(
            ct_bf, qw_bf, skbuf, COMP_, H_, H_, H_ / SK_);
        sk_reduce<<<1024, blk, 0, stream>>>(
            skbuf, COMP_ * H_ / 4, H_ / 4, nullptr, nullptr, 0.125f * LOG2E_,
            nullptr, qb_bf);

        // k|v = [hidden; compressed] @ [k_w; v_w]^T   [split-K, fused]
        mfma_gemm_sk<<<dim3(KV2_ / 128, TOT_ / 128, SK_), blk, 0, stream>>>(
            hidcomp, kvw_bf, skbuf, TOT_, KV2_, H_, H_ / SK_);
        sk_reduce<<<1024, blk, 0, stream>>>(
            skbuf, TOT_ * KV2_ / 4, KV2_ / 4, nullptr, nullptr, 1.f, nullptr, kvb_bf);

        // vt = transpose of v half (row-stride KV2_)
        tpose64<<<dim3(TOT_ / 64, KV_ / 64), blk, 0, stream>>>(
            kvb_bf + KV_, vt_bf, TOT_, KV_, KV2_);

        // attention (MFMA flash, KV-split) + merge
        attn_mfma<<<dim3(COMP_ / 64, NH_, SP_), blk, 0, stream>>>(
            qb_bf, kvb_bf, KV2_, vt_bf, attp, mlbuf);
        attn_merge<<<512, blk, 0, stream>>>(attp, mlbuf, ob_bf, COMP_ * H_ / 4);

        // compressed = o @ o_w^T + ct   [split-K]
        mfma_gemm_sk<<<dim3(H_ / 128, COMP_ / 128, SK_), blk, 0, stream>>>(
            ob_bf, ow_bf, skbuf, COMP_, H_, H_, H_ / SK_);
        sk_reduce<<<1024, blk, 0, stream>>>(
            skbuf, COMP_ * H_ / 4, H_ / 4, nullptr, ct, 1.f, comp1, nullptr);

        rmsnorm_dual_k<<<COMP_, blk, 0, stream>>>(comp1, mlp_norm_w, ct2, ct2_bf);

        // gate|up fused (grid 88x8 = 704 blocks)
        mfma_gemm<<<dim3(GU2_ / 128, COMP_ / 128), blk, 0, stream>>>(
            ct2_bf, guw_bf, nullptr, nullptr, 1.f, nullptr, gub, COMP_, GU2_, H_);

        silu_mul_gu<<<1024, blk, 0, stream>>>(gub, gb_bf, COMP_ * FF_ / 4);

        // compressed = g @ down_w^T + ct2   [split-K, Kc = 1408]
        float* dst = (d == 1) ? out : comp0;
        ushort* dst_bf = (d == 1) ? nullptr : cur_bf;
        mfma_gemm_sk<<<dim3(H_ / 128, COMP_ / 128, SK_), blk, 0, stream>>>(
            gb_bf, down_bf, skbuf, COMP_, H_, FF_, FF_ / SK_);
        sk_reduce<<<1024, blk, 0, stream>>>(
            skbuf, COMP_ * H_ / 4, H_ / 4, nullptr, ct2, 1.f, dst, dst_bf);
        cur = dst;
    }
}

// Round 7
// 924.676 us; speedup vs baseline: 12.3957x; 1.0465x over previous
//
#include <hip/hip_runtime.h>
#include <math.h>

// Problem constants (Compress_30047591202836)
constexpr int S_   = 2048;
constexpr int H_   = 2048;
constexpr int NH_  = 32;
constexpr int NKV_ = 8;
constexpr int HD_  = 64;
constexpr int GROUPS_ = NH_ / NKV_;     // 4
constexpr int KV_  = NKV_ * HD_;        // 512
constexpr int KV2_ = 2 * KV_;           // 1024 (k|v fused)
constexpr int COMP_ = 1024;             // S * 0.5
constexpr int FF_  = 5632;
constexpr int GU2_ = 2 * FF_;           // 11264 (gate|up fused)
constexpr int TOT_ = S_ + COMP_;        // 3072
constexpr float EPS_ = 1e-6f;
constexpr int SK_ = 4;                  // split-K factor (GEMMs)
constexpr int SP_ = 2;                  // KV-split factor (attention)
constexpr float LOG2E_ = 1.44269504088896340736f;

typedef __attribute__((ext_vector_type(4))) float f32x4;
typedef __attribute__((ext_vector_type(8))) short bf16x8;
typedef __attribute__((ext_vector_type(8))) ushort u16x8;

__device__ __forceinline__ ushort f2bf(float x) {
    union { float f; unsigned u; } v; v.f = x;
    unsigned r = v.u + 0x7fffu + ((v.u >> 16) & 1u);   // RNE
    return (ushort)(r >> 16);
}
__device__ __forceinline__ float bf2f(ushort x) {
    union { unsigned u; float f; } v; v.u = ((unsigned)x) << 16;
    return v.f;
}

// ---------------------------------------------------------------------------
// fp32 -> bf16 convert, float4/ushort4 grid-stride. n4 = n/4.
// ---------------------------------------------------------------------------
__global__ __launch_bounds__(256) void f2b_k(
    const float* __restrict__ x, ushort* __restrict__ y, int n4)
{
    int i = blockIdx.x * 256 + threadIdx.x;
    const int stride = gridDim.x * 256;
    for (; i < n4; i += stride) {
        float4 v = ((const float4*)x)[i];
        ushort4 r = {f2bf(v.x), f2bf(v.y), f2bf(v.z), f2bf(v.w)};
        ((ushort4*)y)[i] = r;
    }
}

// ---------------------------------------------------------------------------
// bf16 64x64 tiled transpose: out[(c0+j)*R + r] = in[(r0+r)*ldi + c0+j].
// ---------------------------------------------------------------------------
__global__ __launch_bounds__(256) void tpose64(
    const ushort* __restrict__ in, ushort* __restrict__ out,
    int R, int C, int ldi)
{
    __shared__ ushort T[64][72];
    const int r0 = blockIdx.x * 64, c0 = blockIdx.y * 64;
    const int row = threadIdx.x >> 2, seg = threadIdx.x & 3;

    const ushort* g = &in[(size_t)(r0 + row) * ldi + c0 + seg * 16];
    *(u16x8*)&T[row][seg * 16]     = *(const u16x8*)g;
    *(u16x8*)&T[row][seg * 16 + 8] = *(const u16x8*)(g + 8);
    __syncthreads();

    ushort tmp[16];
#pragma unroll
    for (int j = 0; j < 16; j++) tmp[j] = T[seg * 16 + j][row];
    ushort* go = &out[(size_t)(c0 + row) * R + r0 + seg * 16];
    *(u16x8*)go       = *(const u16x8*)&tmp[0];
    *(u16x8*)(go + 8) = *(const u16x8*)&tmp[8];
}

// ---------------------------------------------------------------------------
// bf16 MFMA GEMM (non-split): C = oscale*(A@B^T)+bias+addp -> outf/outb.
// 128x128 tile, BK=32, 4 waves, 4x4 mfma_f32_16x16x32_bf16 per wave.
// ---------------------------------------------------------------------------
__global__ __launch_bounds__(256) void mfma_gemm(
    const ushort* __restrict__ A, const ushort* __restrict__ B,
    const float* __restrict__ addp, const float* __restrict__ bias,
    float oscale, float* __restrict__ outf, ushort* __restrict__ outb,
    int M, int N, int K)
{
    __shared__ ushort Alds[128 * 32];
    __shared__ ushort Blds[128 * 32];

    const int tid  = threadIdx.x;
    const int w    = tid >> 6;
    const int lane = tid & 63;
    const int bm = blockIdx.y, bn = blockIdx.x;
    const int wr = w >> 1, wc = w & 1;
    const int fr = lane & 15;
    const int fq = lane >> 4;
    const int srow = lane >> 2;
    const int skof = (lane & 3) * 8;

    f32x4 acc[4][4];
#pragma unroll
    for (int i = 0; i < 4; i++)
#pragma unroll
        for (int j = 0; j < 4; j++)
            acc[i][j] = (f32x4){0.f, 0.f, 0.f, 0.f};

    for (int k0 = 0; k0 < K; k0 += 32) {
        __syncthreads();
#pragma unroll
        for (int i = 0; i < 2; i++) {
            const int slot = w * 2 + i;
            const ushort* ga = &A[(size_t)(bm * 128 + slot * 16 + srow) * K + k0 + skof];
            __builtin_amdgcn_global_load_lds(
                (const __attribute__((address_space(1))) void*)ga,
                (__attribute__((address_space(3))) void*)&Alds[slot * 512], 16, 0, 0);
            const ushort* gb = &B[(size_t)(bn * 128 + slot * 16 + srow) * K + k0 + skof];
            __builtin_amdgcn_global_load_lds(
                (const __attribute__((address_space(1))) void*)gb,
                (__attribute__((address_space(3))) void*)&Blds[slot * 512], 16, 0, 0);
        }
        __syncthreads();

        bf16x8 a[4], b[4];
#pragma unroll
        for (int mt = 0; mt < 4; mt++)
            a[mt] = *(const bf16x8*)&Alds[(wr * 64 + mt * 16 + fr) * 32 + fq * 8];
#pragma unroll
        for (int nt = 0; nt < 4; nt++)
            b[nt] = *(const bf16x8*)&Blds[(wc * 64 + nt * 16 + fr) * 32 + fq * 8];

#pragma unroll
        for (int mt = 0; mt < 4; mt++)
#pragma unroll
            for (int nt = 0; nt < 4; nt++)
                acc[mt][nt] = __builtin_amdgcn_mfma_f32_16x16x32_bf16(
                    a[mt], b[nt], acc[mt][nt], 0, 0, 0);
    }

#pragma unroll
    for (int mt = 0; mt < 4; mt++) {
#pragma unroll
        for (int nt = 0; nt < 4; nt++) {
#pragma unroll
            for (int r = 0; r < 4; r++) {
                const int row = bm * 128 + wr * 64 + mt * 16 + fq * 4 + r;
                const int col = bn * 128 + wc * 64 + nt * 16 + fr;
                float v = acc[mt][nt][r] * oscale;
                if (bias) v += bias[row];
                if (addp) v += addp[(size_t)row * N + col];
                if (outf) outf[(size_t)row * N + col] = v;
                if (outb) outb[(size_t)row * N + col] = f2bf(v);
            }
        }
    }
}

// ---------------------------------------------------------------------------
// Split-K MFMA GEMM: grid.z = SK slices of K. Raw fp32 partials to part.
// ---------------------------------------------------------------------------
__global__ __launch_bounds__(256) void mfma_gemm_sk(
    const ushort* __restrict__ A, const ushort* __restrict__ B,
    float* __restrict__ part, int M, int N, int K, int Kc)
{
    __shared__ ushort Alds[128 * 32];
    __shared__ ushort Blds[128 * 32];

    const int tid  = threadIdx.x;
    const int w    = tid >> 6;
    const int lane = tid & 63;
    const int bm = blockIdx.y, bn = blockIdx.x, z = blockIdx.z;
    const int wr = w >> 1, wc = w & 1;
    const int fr = lane & 15;
    const int fq = lane >> 4;
    const int srow = lane >> 2;
    const int skof = (lane & 3) * 8;

    f32x4 acc[4][4];
#pragma unroll
    for (int i = 0; i < 4; i++)
#pragma unroll
        for (int j = 0; j < 4; j++)
            acc[i][j] = (f32x4){0.f, 0.f, 0.f, 0.f};

    const int kbeg = z * Kc;
    for (int k0 = kbeg; k0 < kbeg + Kc; k0 += 32) {
        __syncthreads();
#pragma unroll
        for (int i = 0; i < 2; i++) {
            const int slot = w * 2 + i;
            const ushort* ga = &A[(size_t)(bm * 128 + slot * 16 + srow) * K + k0 + skof];
            __builtin_amdgcn_global_load_lds(
                (const __attribute__((address_space(1))) void*)ga,
                (__attribute__((address_space(3))) void*)&Alds[slot * 512], 16, 0, 0);
            const ushort* gb = &B[(size_t)(bn * 128 + slot * 16 + srow) * K + k0 + skof];
            __builtin_amdgcn_global_load_lds(
                (const __attribute__((address_space(1))) void*)gb,
                (__attribute__((address_space(3))) void*)&Blds[slot * 512], 16, 0, 0);
        }
        __syncthreads();

        bf16x8 a[4], b[4];
#pragma unroll
        for (int mt = 0; mt < 4; mt++)
            a[mt] = *(const bf16x8*)&Alds[(wr * 64 + mt * 16 + fr) * 32 + fq * 8];
#pragma unroll
        for (int nt = 0; nt < 4; nt++)
            b[nt] = *(const bf16x8*)&Blds[(wc * 64 + nt * 16 + fr) * 32 + fq * 8];

#pragma unroll
        for (int mt = 0; mt < 4; mt++)
#pragma unroll
            for (int nt = 0; nt < 4; nt++)
                acc[mt][nt] = __builtin_amdgcn_mfma_f32_16x16x32_bf16(
                    a[mt], b[nt], acc[mt][nt], 0, 0, 0);
    }

    float* pz = part + (size_t)z * M * N;
#pragma unroll
    for (int mt = 0; mt < 4; mt++)
#pragma unroll
        for (int nt = 0; nt < 4; nt++)
#pragma unroll
            for (int r = 0; r < 4; r++) {
                const int row = bm * 128 + wr * 64 + mt * 16 + fq * 4 + r;
                const int col = bn * 128 + wc * 64 + nt * 16 + fr;
                pz[(size_t)row * N + col] = acc[mt][nt][r];
            }
}

// ---------------------------------------------------------------------------
// Split-K reduce + epilogue.
// ---------------------------------------------------------------------------
__global__ __launch_bounds__(256) void sk_reduce(
    const float* __restrict__ part, int mn4, int n4,
    const float* __restrict__ bias, const float* __restrict__ addp,
    float oscale, float* __restrict__ outf, ushort* __restrict__ outb)
{
    const size_t mn = (size_t)mn4 * 4;
    int i = blockIdx.x * 256 + threadIdx.x;
    const int stride = gridDim.x * 256;
    for (; i < mn4; i += stride) {
        float4 v = ((const float4*)part)[i];
#pragma unroll
        for (int z = 1; z < SK_; z++) {
            const float4 pz = ((const float4*)(part + z * mn))[i];
            v.x += pz.x; v.y += pz.y; v.z += pz.z; v.w += pz.w;
        }
        v.x *= oscale; v.y *= oscale; v.z *= oscale; v.w *= oscale;
        if (bias) {
            const float bb = bias[i / n4];
            v.x += bb; v.y += bb; v.z += bb; v.w += bb;
        }
        if (addp) {
            const float4 ad = ((const float4*)addp)[i];
            v.x += ad.x; v.y += ad.y; v.z += ad.z; v.w += ad.w;
        }
        if (outf) ((float4*)outf)[i] = v;
        if (outb) {
            ushort4 r = {f2bf(v.x), f2bf(v.y), f2bf(v.z), f2bf(v.w)};
            ((ushort4*)outb)[i] = r;
        }
    }
}

// ---------------------------------------------------------------------------
// MFMA flash attention, KV-split, S^T formulation.
//   q : (COMP_, H_) bf16, PRE-SCALED by log2(e)/sqrt(HD)  (exp2 domain)
//   k : fused kv buffer rows, row-stride ldk (k half)
//   vt: (KV_, TOT_) bf16 transposed V
// S^T = K·Q^T per key-tile: C-layout gives lane (fr,fq) row qrow=fr, keys
// nt*16+fq*4+r — softmax is in-lane + 2 shuffles, and P stores are 4x b64
// (contiguous in key) instead of 16x b16. Q fragments load straight from
// global (B-operand layout), no Q LDS array. LDS = 3 x 9 KB = 27 KB.
// Emits unnormalized fp32 O-partials (attp[z]) + per-row (m,l) pairs (ml).
// ---------------------------------------------------------------------------
__global__ __launch_bounds__(256) void attn_mfma(
    const ushort* __restrict__ q, const ushort* __restrict__ k, int ldk,
    const ushort* __restrict__ vt, float* __restrict__ attp,
    float* __restrict__ ml)
{
    constexpr int LDT = 72;
    constexpr int KSPAN = TOT_ / SP_;   // 1536 keys per split
    __shared__ ushort Ks[64 * LDT];
    __shared__ ushort Vs[64 * LDT];
    __shared__ ushort Ps[64 * LDT];

    const int qt = blockIdx.x, h = blockIdx.y, z = blockIdx.z;
    const int kvh = h / GROUPS_;
    const int tid = threadIdx.x;
    const int w = tid >> 6, lane = tid & 63;
    const int fr = lane & 15, fq = lane >> 4;
    const int q0 = qt * 64;

    // Q B-fragments straight from global: B[n=fr][k=fq*8+j] (+32 half)
    const ushort* qrow = &q[(size_t)(q0 + w * 16 + fr) * H_ + h * HD_];
    const bf16x8 bq0 = *(const bf16x8*)(qrow + fq * 8);
    const bf16x8 bq1 = *(const bf16x8*)(qrow + 32 + fq * 8);

    float m = -1e30f, l = 0.f;          // per-lane row state (row = fr)
    f32x4 acc[4];
#pragma unroll
    for (int nt = 0; nt < 4; nt++) acc[nt] = (f32x4){0.f, 0.f, 0.f, 0.f};

    const int t_beg = z * KSPAN;
    for (int t0 = t_beg; t0 < t_beg + KSPAN; t0 += 64) {
        __syncthreads();   // all waves done reading prev Ks/Vs
        {
            const int row = tid >> 2, seg = tid & 3;
            const ushort* gk = &k[(size_t)(t0 + row) * ldk + kvh * HD_ + seg * 16];
            u16x8 k0v = *(const u16x8*)gk;
            u16x8 k1v = *(const u16x8*)(gk + 8);
            const ushort* gv = &vt[(size_t)(kvh * HD_ + row) * TOT_ + t0 + seg * 16];
            u16x8 v0v = *(const u16x8*)gv;
            u16x8 v1v = *(const u16x8*)(gv + 8);
            *(u16x8*)&Ks[row * LDT + seg * 16]     = k0v;
            *(u16x8*)&Ks[row * LDT + seg * 16 + 8] = k1v;
            *(u16x8*)&Vs[row * LDT + seg * 16]     = v0v;
            *(u16x8*)&Vs[row * LDT + seg * 16 + 8] = v1v;
        }
        __syncthreads();

        // ---- S^T = K·Q^T : st[nt][r] = S[qrow=fr][key=nt*16+fq*4+r] ----
        f32x4 st[4];
#pragma unroll
        for (int nt = 0; nt < 4; nt++) {
            bf16x8 a0 = *(const bf16x8*)&Ks[(nt * 16 + fr) * LDT + fq * 8];
            bf16x8 a1 = *(const bf16x8*)&Ks[(nt * 16 + fr) * LDT + 32 + fq * 8];
            f32x4 t = (f32x4){0.f, 0.f, 0.f, 0.f};
            t = __builtin_amdgcn_mfma_f32_16x16x32_bf16(a0, bq0, t, 0, 0, 0);
            t = __builtin_amdgcn_mfma_f32_16x16x32_bf16(a1, bq1, t, 0, 0, 0);
            st[nt] = t;
        }

        // ---- per-lane online softmax (row fr; keys split across fq) ----
        float mt = st[0][0];
#pragma unroll
        for (int nt = 0; nt < 4; nt++)
#pragma unroll
            for (int r = 0; r < 4; r++) mt = fmaxf(mt, st[nt][r]);
        mt = fmaxf(mt, __shfl_xor(mt, 16));
        mt = fmaxf(mt, __shfl_xor(mt, 32));
        const float mn = fmaxf(m, mt);
        const float alpha = exp2f(m - mn);
        m = mn;
        float ss = 0.f;
#pragma unroll
        for (int nt = 0; nt < 4; nt++)
#pragma unroll
            for (int r = 0; r < 4; r++) {
                const float pv = exp2f(st[nt][r] - mn);
                st[nt][r] = pv;
                ss += pv;
            }
        ss += __shfl_xor(ss, 16);
        ss += __shfl_xor(ss, 32);
        l = l * alpha + ss;

        // ---- P -> LDS, 4x b64 (keys contiguous per lane) ----
#pragma unroll
        for (int nt = 0; nt < 4; nt++) {
            ushort4 pk = {f2bf(st[nt][0]), f2bf(st[nt][1]),
                          f2bf(st[nt][2]), f2bf(st[nt][3])};
            *(ushort4*)&Ps[(w * 16 + fr) * LDT + nt * 16 + fq * 4] = pk;
        }

        // ---- PV: O += P·V (A=P rows, B=V^T) ----
        bf16x8 ap0 = *(const bf16x8*)&Ps[(w * 16 + fr) * LDT + fq * 8];
        bf16x8 ap1 = *(const bf16x8*)&Ps[(w * 16 + fr) * LDT + 32 + fq * 8];
        float ar[4];
#pragma unroll
        for (int r = 0; r < 4; r++) ar[r] = __shfl(alpha, fq * 4 + r, 16);
#pragma unroll
        for (int nt = 0; nt < 4; nt++) {
            bf16x8 b0 = *(const bf16x8*)&Vs[(nt * 16 + fr) * LDT + fq * 8];
            bf16x8 b1 = *(const bf16x8*)&Vs[(nt * 16 + fr) * LDT + 32 + fq * 8];
            f32x4 t = acc[nt];
            t[0] *= ar[0]; t[1] *= ar[1]; t[2] *= ar[2]; t[3] *= ar[3];
            t = __builtin_amdgcn_mfma_f32_16x16x32_bf16(ap0, b0, t, 0, 0, 0);
            t = __builtin_amdgcn_mfma_f32_16x16x32_bf16(ap1, b1, t, 0, 0, 0);
            acc[nt] = t;
        }
    }

    // ---- epilogue: unnormalized partial + (m,l) out ----
    float* pz = attp + (size_t)z * COMP_ * H_;
#pragma unroll
    for (int r = 0; r < 4; r++) {
        const int row = q0 + w * 16 + fq * 4 + r;
#pragma unroll
        for (int nt = 0; nt < 4; nt++)
            pz[(size_t)row * H_ + h * HD_ + nt * 16 + fr] = acc[nt][r];
    }
    if (lane < 16)   // fq == 0 lanes hold state for row fr = lane
        ((float2*)ml)[((size_t)z * NH_ + h) * COMP_ + (q0 + w * 16 + fr)] =
            make_float2(m, l);
}

// ---------------------------------------------------------------------------
// Merge the SP_ KV-splits: o = (sum_z a_z * attp_z) / (sum_z a_z * l_z),
// a_z = 2^(m_z - M). n4 = COMP_*H_/4.
// ---------------------------------------------------------------------------
__global__ __launch_bounds__(256) void attn_merge(
    const float* __restrict__ attp, const float* __restrict__ ml,
    ushort* __restrict__ o, int n4)
{
    constexpr int H4 = H_ / 4;
    constexpr size_t PS = (size_t)COMP_ * H_;
    int i = blockIdx.x * 256 + threadIdx.x;
    const int stride = gridDim.x * 256;
    for (; i < n4; i += stride) {
        const int row = i / H4;
        const int col = (i - row * H4) * 4;
        const int h = col >> 6;          // HD_ = 64
        const float2 ml0 = ((const float2*)ml)[((size_t)0 * NH_ + h) * COMP_ + row];
        const float2 ml1 = ((const float2*)ml)[((size_t)1 * NH_ + h) * COMP_ + row];
        const float M = fmaxf(ml0.x, ml1.x);
        const float a0 = exp2f(ml0.x - M), a1 = exp2f(ml1.x - M);
        const float inv = 1.0f / (a0 * ml0.y + a1 * ml1.y);
        const float4 p0 = ((const float4*)attp)[i];
        const float4 p1 = ((const float4*)(attp + PS))[i];
        ushort4 r = {f2bf((a0 * p0.x + a1 * p1.x) * inv),
                     f2bf((a0 * p0.y + a1 * p1.y) * inv),
                     f2bf((a0 * p0.z + a1 * p1.z) * inv),
                     f2bf((a0 * p0.w + a1 * p1.w) * inv)};
        ((ushort4*)o)[i] = r;
    }
}

// ---------------------------------------------------------------------------
// RMSNorm, dual fp32 + bf16 output. One block (256 threads) per row.
// ---------------------------------------------------------------------------
__global__ __launch_bounds__(256) void rmsnorm_dual_k(
    const float* __restrict__ x, const float* __restrict__ w,
    float* __restrict__ y, ushort* __restrict__ yb)
{
    const int row = blockIdx.x;
    const float* xr = x + (size_t)row * H_;
    __shared__ float red[256];

    float s = 0.f;
#pragma unroll
    for (int i = 0; i < 8; i++) {
        const float v = xr[threadIdx.x + i * 256];
        s += v * v;
    }
    red[threadIdx.x] = s;
    __syncthreads();
    for (int t = 128; t > 0; t >>= 1) {
        if (threadIdx.x < t) red[threadIdx.x] += red[threadIdx.x + t];
        __syncthreads();
    }
    const float scale = rsqrtf(red[0] * (1.0f / H_) + EPS_);
#pragma unroll
    for (int i = 0; i < 8; i++) {
        const int idx = threadIdx.x + i * 256;
        const float v = xr[idx] * scale * w[idx];
        y[(size_t)row * H_ + idx] = v;
        yb[(size_t)row * H_ + idx] = f2bf(v);
    }
}

// ---------------------------------------------------------------------------
// Fused-gate/up silu-mul: g_out[row][c] = silu(gu[row][c]) * gu[row][FF+c].
// ---------------------------------------------------------------------------
__global__ __launch_bounds__(256) void silu_mul_gu(
    const ushort* __restrict__ gu, ushort* __restrict__ g, int n4)
{
    constexpr int FF4 = FF_ / 4;
    int i = blockIdx.x * 256 + threadIdx.x;
    const int stride = gridDim.x * 256;
    for (; i < n4; i += stride) {
        const int row = i / FF4;
        const int c = (i - row * FF4) * 4;
        ushort4 gv = *(const ushort4*)&gu[(size_t)row * GU2_ + c];
        ushort4 uv = *(const ushort4*)&gu[(size_t)row * GU2_ + FF_ + c];
        float x0 = bf2f(gv.x), x1 = bf2f(gv.y), x2 = bf2f(gv.z), x3 = bf2f(gv.w);
        x0 = x0 / (1.f + __expf(-x0)) * bf2f(uv.x);
        x1 = x1 / (1.f + __expf(-x1)) * bf2f(uv.y);
        x2 = x2 / (1.f + __expf(-x2)) * bf2f(uv.z);
        x3 = x3 / (1.f + __expf(-x3)) * bf2f(uv.w);
        ushort4 r = {f2bf(x0), f2bf(x1), f2bf(x2), f2bf(x3)};
        ((ushort4*)g)[i] = r;
    }
}

// ---------------------------------------------------------------------------
extern "C" void kernel_launch(void* const* d_in, const int* in_sizes, int n_in,
                              void* d_out, int out_size, void* d_ws, size_t ws_size,
                              hipStream_t stream)
{
    (void)in_sizes; (void)n_in; (void)out_size; (void)ws_size;

    const float* hidden      = (const float*)d_in[0];
    const float* comp_w      = (const float*)d_in[1];
    const float* comp_b      = (const float*)d_in[2];
    const float* q_w         = (const float*)d_in[3];
    const float* k_w         = (const float*)d_in[4];
    const float* v_w         = (const float*)d_in[5];
    const float* o_w         = (const float*)d_in[6];
    const float* attn_norm_w = (const float*)d_in[7];
    const float* mlp_norm_w  = (const float*)d_in[8];
    const float* gate_w      = (const float*)d_in[9];
    const float* up_w        = (const float*)d_in[10];
    const float* down_w      = (const float*)d_in[11];
    float* out = (float*)d_out;

    char* p = (char*)d_ws;
    auto alloc = [&](size_t bytes) -> char* {
        char* r = p; p += (bytes + 255) & ~(size_t)255; return r;
    };
    // bf16 weights (kv and gate/up fused = stacked rows)
    ushort* qw_bf    = (ushort*)alloc((size_t)H_ * H_ * 2);
    ushort* kvw_bf   = (ushort*)alloc((size_t)KV2_ * H_ * 2);
    ushort* ow_bf    = (ushort*)alloc((size_t)H_ * H_ * 2);
    ushort* guw_bf   = (ushort*)alloc((size_t)GU2_ * H_ * 2);
    ushort* down_bf  = (ushort*)alloc((size_t)H_ * FF_ * 2);
    ushort* compw_bf = (ushort*)alloc((size_t)COMP_ * S_ * 2);
    // bf16 activation buffers
    ushort* hidcomp  = (ushort*)alloc((size_t)TOT_ * H_ * 2);   // [hidden; compressed]
    ushort* hidT     = (ushort*)alloc((size_t)H_ * S_ * 2);
    ushort* ct_bf    = (ushort*)alloc((size_t)COMP_ * H_ * 2);
    ushort* ct2_bf   = (ushort*)alloc((size_t)COMP_ * H_ * 2);
    ushort* ob_bf    = (ushort*)alloc((size_t)COMP_ * H_ * 2);
    ushort* qb_bf    = (ushort*)alloc((size_t)COMP_ * H_ * 2);
    ushort* kvb_bf   = (ushort*)alloc((size_t)TOT_ * KV2_ * 2); // k cols 0..511, v cols 512..1023
    ushort* vt_bf    = (ushort*)alloc((size_t)KV_ * TOT_ * 2);
    ushort* gb_bf    = (ushort*)alloc((size_t)COMP_ * FF_ * 2);
    // fp32 activations (residual chain)
    float* comp0 = (float*)alloc((size_t)COMP_ * H_ * 4);
    float* comp1 = (float*)alloc((size_t)COMP_ * H_ * 4);
    float* ct    = (float*)alloc((size_t)COMP_ * H_ * 4);
    float* ct2   = (float*)alloc((size_t)COMP_ * H_ * 4);
    // split-K scratch; time-shared with gate|up C and attention partials
    float*  skbuf = (float*)alloc((size_t)SK_ * TOT_ * KV2_ * 4);
    ushort* gub   = (ushort*)skbuf;                       // (COMP_, GU2_) bf16
    float*  attp  = skbuf;                                // SP_ x (COMP_, H_) fp32 = 16 MB
    float*  mlbuf = skbuf + (size_t)SP_ * COMP_ * H_;     // SP_*NH_*COMP_ float2

    ushort* cur_bf = hidcomp + (size_t)S_ * H_;   // compressed rows of hidcomp

    const dim3 blk(256);

    // ---- one-time converts ----
    f2b_k<<<512, blk, 0, stream>>>(q_w,    qw_bf,            H_ * H_ / 4);
    f2b_k<<<512, blk, 0, stream>>>(k_w,    kvw_bf,           KV_ * H_ / 4);
    f2b_k<<<512, blk, 0, stream>>>(v_w,    kvw_bf + (size_t)KV_ * H_, KV_ * H_ / 4);
    f2b_k<<<512, blk, 0, stream>>>(o_w,    ow_bf,            H_ * H_ / 4);
    f2b_k<<<512, blk, 0, stream>>>(gate_w, guw_bf,           FF_ * H_ / 4);
    f2b_k<<<512, blk, 0, stream>>>(up_w,   guw_bf + (size_t)FF_ * H_, FF_ * H_ / 4);
    f2b_k<<<512, blk, 0, stream>>>(down_w, down_bf,          H_ * FF_ / 4);
    f2b_k<<<512, blk, 0, stream>>>(comp_w, compw_bf,         COMP_ * S_ / 4);
    f2b_k<<<512, blk, 0, stream>>>(hidden, hidcomp,          S_ * H_ / 4);
    tpose64<<<dim3(S_ / 64, H_ / 64), blk, 0, stream>>>(hidcomp, hidT, S_, H_, H_);

    // compressed = comp_w @ hidden + comp_b  (split-K via B = hid^T)
    mfma_gemm_sk<<<dim3(H_ / 128, COMP_ / 128, SK_), blk, 0, stream>>>(
        compw_bf, hidT, skbuf, COMP_, H_, S_, S_ / SK_);
    sk_reduce<<<1024, blk, 0, stream>>>(
        skbuf, COMP_ * H_ / 4, H_ / 4, comp_b, nullptr, 1.f, comp0, cur_bf);

    float* cur = comp0;
    for (int d = 0; d < 2; d++) {
        rmsnorm_dual_k<<<COMP_, blk, 0, stream>>>(cur, attn_norm_w, ct, ct_bf);

        // q = (log2e/8) * (ct @ q_w^T)   [split-K; exp2-domain scaling]
        mfma_gemm_sk<<<dim3(H_ / 128, COMP_ / 128, SK_), blk, 0, stream>>>(
            ct_bf, qw_bf, skbuf, COMP_, H_, H_, H_ / SK_);
        sk_reduce<<<1024, blk, 0, stream>>>(
            skbuf, COMP_ * H_ / 4, H_ / 4, nullptr, nullptr, 0.125f * LOG2E_,
            nullptr, qb_bf);

        // k|v = [hidden; compressed] @ [k_w; v_w]^T   [split-K, fused]
        mfma_gemm_sk<<<dim3(KV2_ / 128, TOT_ / 128, SK_), blk, 0, stream>>>(
            hidcomp, kvw_bf, skbuf, TOT_, KV2_, H_, H_ / SK_);
        sk_reduce<<<1024, blk, 0, stream>>>(
            skbuf, TOT_ * KV2_ / 4, KV2_ / 4, nullptr, nullptr, 1.f, nullptr, kvb_bf);

        // vt = transpose of v half (row-stride KV2_)
        tpose64<<<dim3(TOT_ / 64, KV_ / 64), blk, 0, stream>>>(
            kvb_bf + KV_, vt_bf, TOT_, KV_, KV2_);

        // attention (MFMA flash, S^T formulation, KV-split) + merge
        attn_mfma<<<dim3(COMP_ / 64, NH_, SP_), blk, 0, stream>>>(
            qb_bf, kvb_bf, KV2_, vt_bf, attp, mlbuf);
        attn_merge<<<512, blk, 0, stream>>>(attp, mlbuf, ob_bf, COMP_ * H_ / 4);

        // compressed = o @ o_w^T + ct   [split-K]
        mfma_gemm_sk<<<dim3(H_ / 128, COMP_ / 128, SK_), blk, 0, stream>>>(
            ob_bf, ow_bf, skbuf, COMP_, H_, H_, H_ / SK_);
        sk_reduce<<<1024, blk, 0, stream>>>(
            skbuf, COMP_ * H_ / 4, H_ / 4, nullptr, ct, 1.f, comp1, nullptr);

        rmsnorm_dual_k<<<COMP_, blk, 0, stream>>>(comp1, mlp_norm_w, ct2, ct2_bf);

        // gate|up fused (grid 88x8 = 704 blocks)
        mfma_gemm<<<dim3(GU2_ / 128, COMP_ / 128), blk, 0, stream>>>(
            ct2_bf, guw_bf, nullptr, nullptr, 1.f, nullptr, gub, COMP_, GU2_, H_);

        silu_mul_gu<<<1024, blk, 0, stream>>>(gub, gb_bf, COMP_ * FF_ / 4);

        // compressed = g @ down_w^T + ct2   [split-K, Kc = 1408]
        float* dst = (d == 1) ? out : comp0;
        ushort* dst_bf = (d == 1) ? nullptr : cur_bf;
        mfma_gemm_sk<<<dim3(H_ / 128, COMP_ / 128, SK_), blk, 0, stream>>>(
            gb_bf, down_bf, skbuf, COMP_, H_, FF_, FF_ / SK_);
        sk_reduce<<<1024, blk, 0, stream>>>(
            skbuf, COMP_ * H_ / 4, H_ / 4, nullptr, ct2, 1.f, dst, dst_bf);
        cur = dst;
    }
}